// Round 10
// baseline (1453.629 us; speedup 1.0000x reference)
//
#include <hip/hip_runtime.h>
#include <hip/hip_cooperative_groups.h>
#include <hip/hip_fp16.h>
#include <math.h>

namespace cg = cooperative_groups;

#define NN 50000
#define EE 800000
#define NHEAD 8
#define BN_EPS 1e-5f
#define NSEG 196   // ceil(NN/256)
#define CGB 1024   // cooperative grid blocks

typedef _Float16 half8_t __attribute__((ext_vector_type(8)));
typedef float float4_t __attribute__((ext_vector_type(4)));

// monotone float<->uint encoding for atomicMax on signed floats
__device__ __forceinline__ unsigned fenc(float f) {
  unsigned u = __float_as_uint(f);
  return (u & 0x80000000u) ? ~u : (u | 0x80000000u);
}
__device__ __forceinline__ float fdec(unsigned k) {
  return (k & 0x80000000u) ? __uint_as_float(k & 0x7fffffffu)
                           : __uint_as_float(~k);
}

// bn scale/shift from raw sums (stats[c]=sum, stats[128+c]=sumsq)
__device__ __forceinline__ void bn_coef(const float* __restrict__ stats,
                                        const float* __restrict__ gamma,
                                        const float* __restrict__ beta,
                                        int c, float& sc, float& sh) {
  float mean = stats[c] * (1.f / NN);
  float var = fmaxf(stats[128 + c] * (1.f / NN) - mean * mean, 0.f);
  sc = gamma[c] * rsqrtf(var + BN_EPS);
  sh = beta[c] - mean * sc;
}

// ---------------------------------------------------------------------------
// MFMA GEMM for embed/decision MLPs (unchanged from R9).
// ---------------------------------------------------------------------------
template <int KDIM, int NC, typename AT, bool ABN, bool RESIDBN, bool STATS,
          bool F16OUT, bool F32OUT>
__global__ __launch_bounds__(256)
void mfma_gemm_k(const AT* __restrict__ A, const _Float16* __restrict__ Bt,
                 const float* __restrict__ bn, const float* __restrict__ gamma,
                 const float* __restrict__ beta, float* __restrict__ statsOut,
                 const float* __restrict__ residf, _Float16* __restrict__ Ch,
                 float* __restrict__ Cf, int M) {
  constexpr int NT = NC / 16;
  const int lane = threadIdx.x & 63, wave = threadIdx.x >> 6;
  const int q = lane >> 4, l16 = lane & 15;
  const int row0 = blockIdx.x * 128 + wave * 32;
  float4_t acc[2][NT];
#pragma unroll
  for (int i = 0; i < 2; ++i)
#pragma unroll
    for (int j = 0; j < NT; ++j) acc[i][j] = (float4_t){0.f, 0.f, 0.f, 0.f};

#pragma unroll
  for (int kk = 0; kk < KDIM / 32; ++kk) {
    float scv[8], shv[8];
    if constexpr (ABN) {
      int kb = kk * 32 + q * 8;
#pragma unroll
      for (int x = 0; x < 8; ++x) bn_coef(bn, gamma, beta, kb + x, scv[x], shv[x]);
    }
    half8_t a[2];
#pragma unroll
    for (int i = 0; i < 2; ++i) {
      int r = row0 + i * 16 + l16;
      r = (r < M) ? r : (M - 1);
      if constexpr (__is_same(AT, _Float16)) {
        a[i] = *(const half8_t*)(A + (size_t)r * KDIM + kk * 32 + q * 8);
      } else {
        const float* ap = (const float*)A + (size_t)r * KDIM + kk * 32 + q * 8;
        float4 v0 = *(const float4*)ap, v1 = *(const float4*)(ap + 4);
        float t[8] = {v0.x, v0.y, v0.z, v0.w, v1.x, v1.y, v1.z, v1.w};
        if constexpr (ABN) {
#pragma unroll
          for (int x = 0; x < 8; ++x) t[x] = fmaxf(t[x] * scv[x] + shv[x], 0.f);
        }
        half8_t hv;
#pragma unroll
        for (int x = 0; x < 8; ++x) hv[x] = (_Float16)t[x];
        a[i] = hv;
      }
    }
#pragma unroll
    for (int j = 0; j < NT; ++j) {
      half8_t b = *(const half8_t*)(Bt + (size_t)(j * 16 + l16) * KDIM + kk * 32 + q * 8);
      acc[0][j] = __builtin_amdgcn_mfma_f32_16x16x32_f16(a[0], b, acc[0][j], 0, 0, 0);
      acc[1][j] = __builtin_amdgcn_mfma_f32_16x16x32_f16(a[1], b, acc[1][j], 0, 0, 0);
    }
  }

  float rsc[NT], rsh[NT];
  if constexpr (RESIDBN) {
#pragma unroll
    for (int j = 0; j < NT; ++j) bn_coef(bn, gamma, beta, j * 16 + l16, rsc[j], rsh[j]);
  }
#pragma unroll
  for (int i = 0; i < 2; ++i)
#pragma unroll
    for (int j = 0; j < NT; ++j)
#pragma unroll
      for (int r = 0; r < 4; ++r) {
        int row = row0 + i * 16 + q * 4 + r;   // C/D: col=lane&15, row=q*4+reg
        if (row >= M) continue;
        int col = j * 16 + l16;
        float v = acc[i][j][r];
        if constexpr (RESIDBN) {
          float rv = residf[(size_t)row * NC + col];
          v += fmaxf(rv * rsc[j] + rsh[j], 0.f);
        }
        if constexpr (F32OUT) Cf[(size_t)row * NC + col] = v;
        if constexpr (F16OUT) Ch[(size_t)row * NC + col] = (_Float16)v;
      }

  if constexpr (STATS) {
    float sc_[NT], sq_[NT];
#pragma unroll
    for (int j = 0; j < NT; ++j) {
      float s = 0.f, qq = 0.f;
#pragma unroll
      for (int i = 0; i < 2; ++i)
#pragma unroll
        for (int r = 0; r < 4; ++r) {
          int row = row0 + i * 16 + q * 4 + r;
          float x = (row < M) ? acc[i][j][r] : 0.f;
          s += x; qq += x * x;
        }
      sc_[j] = s; sq_[j] = qq;
    }
#pragma unroll
    for (int j = 0; j < NT; ++j) {
      sc_[j] += __shfl_xor(sc_[j], 16, 64);
      sq_[j] += __shfl_xor(sq_[j], 16, 64);
      sc_[j] += __shfl_xor(sc_[j], 32, 64);
      sq_[j] += __shfl_xor(sq_[j], 32, 64);
    }
    if (lane < 16) {
#pragma unroll
      for (int j = 0; j < NT; ++j) {
        atomicAdd(&statsOut[j * 16 + l16], sc_[j]);
        atomicAdd(&statsOut[128 + j * 16 + l16], sq_[j]);
      }
    }
  }
}

// ---------------------------------------------------------------------------
// Merged per-layer GAT GEMM, NC=288 (unchanged from R9).
// ---------------------------------------------------------------------------
__global__ __launch_bounds__(256)
void feat_gemm_k(const _Float16* __restrict__ A, const _Float16* __restrict__ Bt,
                 _Float16* __restrict__ feat0, _Float16* __restrict__ feat1,
                 float* __restrict__ el0, float* __restrict__ er0,
                 float* __restrict__ el1, float* __restrict__ er1,
                 unsigned* __restrict__ elmax, int M) {
  constexpr int NT = 18;
  const int lane = threadIdx.x & 63, wave = threadIdx.x >> 6;
  const int q = lane >> 4, l16 = lane & 15;
  const int row0 = blockIdx.x * 128 + wave * 32;
  float4_t acc[2][NT];
#pragma unroll
  for (int i = 0; i < 2; ++i)
#pragma unroll
    for (int j = 0; j < NT; ++j) acc[i][j] = (float4_t){0.f, 0.f, 0.f, 0.f};

#pragma unroll
  for (int kk = 0; kk < 4; ++kk) {
    half8_t a[2];
#pragma unroll
    for (int i = 0; i < 2; ++i) {
      int r = row0 + i * 16 + l16;
      r = (r < M) ? r : (M - 1);
      a[i] = *(const half8_t*)(A + (size_t)r * 128 + kk * 32 + q * 8);
    }
#pragma unroll
    for (int j = 0; j < NT; ++j) {
      half8_t b = *(const half8_t*)(Bt + (size_t)(j * 16 + l16) * 128 + kk * 32 + q * 8);
      acc[0][j] = __builtin_amdgcn_mfma_f32_16x16x32_f16(a[0], b, acc[0][j], 0, 0, 0);
      acc[1][j] = __builtin_amdgcn_mfma_f32_16x16x32_f16(a[1], b, acc[1][j], 0, 0, 0);
    }
  }

#pragma unroll
  for (int i = 0; i < 2; ++i)
#pragma unroll
    for (int r = 0; r < 4; ++r) {
      int row = row0 + i * 16 + q * 4 + r;
      if (row >= M) continue;
#pragma unroll
      for (int j = 0; j < 16; ++j) {
        float v = acc[i][j][r];
        if (j < 8)
          feat0[(size_t)row * 128 + j * 16 + l16] = (_Float16)v;
        else
          feat1[(size_t)row * 128 + (j - 8) * 16 + l16] = (_Float16)v;
      }
      {
        float v = acc[i][16][r];
        if (l16 < 8) el0[(size_t)row * 8 + l16] = v;
        else         er0[(size_t)row * 8 + (l16 - 8)] = v;
        v = acc[i][17][r];
        if (l16 < 8) el1[(size_t)row * 8 + l16] = v;
        else         er1[(size_t)row * 8 + (l16 - 8)] = v;
      }
    }

  float m0 = -1e30f, m1 = -1e30f;
#pragma unroll
  for (int i = 0; i < 2; ++i)
#pragma unroll
    for (int r = 0; r < 4; ++r) {
      m0 = fmaxf(m0, acc[i][16][r]);
      m1 = fmaxf(m1, acc[i][17][r]);
    }
  m0 = fmaxf(m0, __shfl_xor(m0, 16, 64)); m0 = fmaxf(m0, __shfl_xor(m0, 32, 64));
  m1 = fmaxf(m1, __shfl_xor(m1, 16, 64)); m1 = fmaxf(m1, __shfl_xor(m1, 32, 64));
  if (q == 0 && l16 < 8) {
    atomicMax(&elmax[l16], fenc(m0));
    atomicMax(&elmax[8 + l16], fenc(m1));
  }
}

// ---------------------------------------------------------------------------
// Cooperative fused build: zero buffers + weight transposes/merged-Bt, then
// the full CSR chain (hist+rank -> segment scan -> segsum scan -> add offsets
// -> atomic-free uint16 fill) with grid.sync() between phases.
// Replaces 7 dispatches (memset + 5 CSR kernels + build_k) with 1.
// ---------------------------------------------------------------------------
struct BuildArgs {
  const int* src; const int* dst;
  int* cnt; unsigned short* rank; int* rowptr; unsigned short* csr;
  int* segsum;       // 512 ints (2 relations x 256 slots)
  unsigned* elmax;   // 64 (4 layers x 16)
  float* stats;      // 1024
  const float* ew1; const float* ew2; const float* dw1; const float* dw2;
  const float* gfc; const float* gal; const float* gar;
  _Float16* ew1t; _Float16* ew2t; _Float16* dw1t; _Float16* dw2t; _Float16* bt;
};

__global__ __launch_bounds__(256)
void fused_build_k(BuildArgs a) {
  cg::grid_group grid = cg::this_grid();
  const int gtid = blockIdx.x * 256 + threadIdx.x;
  const int gsz = CGB * 256;
  __shared__ int sh[256];

  // ---- phase 0: zero cnt/elmax/stats + weight builds ----
  for (int i = gtid; i < 2 * NN; i += gsz) a.cnt[i] = 0;
  if (gtid < 64) a.elmax[gtid] = 0u;
  if (gtid >= 64 && gtid < 64 + 1024) a.stats[gtid - 64] = 0.f;
  if (blockIdx.x < 4) {
    int b = blockIdx.x;  // layer b merged Bt [288][128]
    _Float16* dst = a.bt + (size_t)b * 288 * 128;
    for (int idx = threadIdx.x; idx < 288 * 128; idx += 256) {
      int c = idx >> 7, k = idx & 127;
      float v;
      if (c < 128) {
        v = a.gfc[(size_t)(2 * b) * 16384 + k * 128 + c];
      } else if (c < 256) {
        v = a.gfc[(size_t)(2 * b + 1) * 16384 + k * 128 + (c - 128)];
      } else {
        int sub = c - 256, blk = sub >> 3, h = sub & 7;
        int r = blk >> 1;
        const float* attn = (blk & 1) ? a.gar : a.gal;
        const float* W = a.gfc + (size_t)(2 * b + r) * 16384;
        const float* av = attn + (size_t)(2 * b + r) * 128 + h * 16;
        float s = 0.f;
#pragma unroll
        for (int d = 0; d < 16; ++d) s += W[k * 128 + h * 16 + d] * av[d];
        v = s;
      }
      dst[idx] = (_Float16)v;
    }
  } else if (blockIdx.x < 8) {
    int j = blockIdx.x - 4;
    const float* srcs[4] = {a.ew1, a.ew2, a.dw1, a.dw2};
    _Float16* dsts[4] = {a.ew1t, a.ew2t, a.dw1t, a.dw2t};
    const int ks[4] = {64, 128, 128, 128}, ns[4] = {128, 128, 128, 32};
    int k = ks[j], nn = ns[j], total = k * nn;
    for (int i = threadIdx.x; i < total; i += 256) {
      int kk = i / nn, cc = i % nn;
      dsts[j][(size_t)cc * k + kk] = (_Float16)srcs[j][i];
    }
  }
  grid.sync();

  // ---- phase 1: hist + per-edge rank ----
  for (int e = gtid; e < 2 * EE; e += gsz) {
    int idx = ((e >= EE) ? NN : 0) + a.dst[e];
    a.rank[e] = (unsigned short)atomicAdd(&a.cnt[idx], 1);
  }
  grid.sync();

  // ---- phase 2: per-segment exclusive scan (one block per 256-segment) ----
  if (blockIdx.x < 2 * NSEG) {
    int r = blockIdx.x / NSEG, ls = blockIdx.x % NSEG;
    int i = ls * 256 + threadIdx.x;
    int v = (i < NN) ? a.cnt[r * NN + i] : 0;
    sh[threadIdx.x] = v;
    __syncthreads();
#pragma unroll
    for (int off = 1; off < 256; off <<= 1) {
      int t = (threadIdx.x >= off) ? sh[threadIdx.x - off] : 0;
      __syncthreads();
      sh[threadIdx.x] += t;
      __syncthreads();
    }
    if (i < NN) a.rowptr[r * (NN + 1) + i] = sh[threadIdx.x] - v;
    if (threadIdx.x == 255) a.segsum[r * 256 + ls] = sh[255];
  }
  grid.sync();

  // ---- phase 3: exclusive scan of segment sums (block 0, per relation) ----
  if (blockIdx.x == 0) {
    for (int r = 0; r < 2; ++r) {
      int v = (threadIdx.x < NSEG) ? a.segsum[r * 256 + threadIdx.x] : 0;
      sh[threadIdx.x] = v;
      __syncthreads();
#pragma unroll
      for (int off = 1; off < 256; off <<= 1) {
        int t = (threadIdx.x >= off) ? sh[threadIdx.x - off] : 0;
        __syncthreads();
        sh[threadIdx.x] += t;
        __syncthreads();
      }
      if (threadIdx.x < NSEG) a.segsum[r * 256 + threadIdx.x] = sh[threadIdx.x] - v;
      __syncthreads();
    }
  }
  grid.sync();

  // ---- phase 4: add segment offsets; close rowptr ----
  for (int i = gtid; i < 2 * NN; i += gsz) {
    int r = i / NN, n = i % NN;
    a.rowptr[r * (NN + 1) + n] += a.segsum[r * 256 + (n >> 8)];
  }
  if (gtid < 2) a.rowptr[gtid * (NN + 1) + NN] = EE;
  grid.sync();

  // ---- phase 5: atomic-free uint16 fill ----
  for (int e = gtid; e < 2 * EE; e += gsz) {
    int r = (e >= EE) ? 1 : 0;
    int d = a.dst[e];
    int p = a.rowptr[r * (NN + 1) + d] + (int)a.rank[e];
    a.csr[(size_t)r * EE + p] = (unsigned short)a.src[e];
  }
}

// ---------------------------------------------------------------------------
// GAT aggregate (unchanged from R9): 8-edge batch, lane-specialized bound-
// shift softmax, no shfl on any address path.
// ---------------------------------------------------------------------------
__device__ __forceinline__ float2 agg_rel(const __half2* __restrict__ feat,
                                          const float* __restrict__ el,
                                          float er_h, float bound,
                                          const unsigned short* __restrict__ csr,
                                          int beg, int end, int lane, int head,
                                          int eslot) {
  float ls = 0.f, a0 = 0.f, a1 = 0.f;
  for (int t = beg; t < end; t += 8) {
    int s[8];
#pragma unroll
    for (int j = 0; j < 8; ++j) s[j] = (int)csr[min(t + j, end - 1)];
    int s_own = (int)csr[min(t + eslot, end - 1)];
    float ev = el[(size_t)s_own * 8 + head];
    __half2 f[8];
#pragma unroll
    for (int j = 0; j < 8; ++j) f[j] = feat[(size_t)s[j] * 64 + lane];
    float e = ev + er_h;
    e = fmaxf(e, 0.2f * e);                    // leaky_relu 0.2
    float p = __expf(e - bound);               // e <= bound, no overflow
    p = (t + eslot < end) ? p : 0.f;           // padded tail -> 0
#pragma unroll
    for (int j = 0; j < 8; ++j) {
      float pj = __shfl(p, (lane & 56) | j);
      float2 fv = __half22float2(f[j]);
      ls += pj; a0 += pj * fv.x; a1 += pj * fv.y;
    }
  }
  float inv = (ls > 0.f) ? 1.f / ls : 0.f;     // isolated node -> rst = 0
  return make_float2(a0 * inv, a1 * inv);
}

__global__ __launch_bounds__(256)
void gat_agg_k(const __half2* __restrict__ f0, const __half2* __restrict__ f1,
               const float* __restrict__ el0, const float* __restrict__ er0,
               const float* __restrict__ el1, const float* __restrict__ er1,
               const int* __restrict__ rowptr, const unsigned short* __restrict__ csr,
               const float* __restrict__ b0, const float* __restrict__ b1,
               const unsigned* __restrict__ elmax,
               float* __restrict__ h1, _Float16* __restrict__ h1h) {
  int n = blockIdx.x * 4 + (threadIdx.x >> 6);
  if (n >= NN) return;
  int lane = threadIdx.x & 63;
  int head = lane >> 3, eslot = lane & 7;
  float er0h = er0[(size_t)n * 8 + head];
  float er1h = er1[(size_t)n * 8 + head];
  float bnd0 = fdec(elmax[head]) + er0h;       bnd0 = fmaxf(bnd0, 0.2f * bnd0);
  float bnd1 = fdec(elmax[8 + head]) + er1h;   bnd1 = fmaxf(bnd1, 0.2f * bnd1);
  float2 r0 = agg_rel(f0, el0, er0h, bnd0, csr, rowptr[n], rowptr[n + 1],
                      lane, head, eslot);
  const int* rp1 = rowptr + (NN + 1);
  float2 r1 = agg_rel(f1, el1, er1h, bnd1, csr + EE, rp1[n], rp1[n + 1],
                      lane, head, eslot);
  float t0 = r0.x + r1.x + b0[lane * 2] + b1[lane * 2];
  float t1 = r0.y + r1.y + b0[lane * 2 + 1] + b1[lane * 2 + 1];
  t0 = (t0 > 0.f) ? t0 : 0.01f * t0;           // leaky_relu 0.01
  t1 = (t1 > 0.f) ? t1 : 0.01f * t1;
  float2* h2p = (float2*)h1 + (size_t)n * 64 + lane;
  float2 h = *h2p;
  h.x += t0; h.y += t1;
  *h2p = h;
  __half2* hh = (__half2*)h1h + (size_t)n * 64 + lane;
  *hh = __floats2half2_rn(h.x, h.y);
}

// ---------------------------------------------------------------------------
extern "C" void kernel_launch(void* const* d_in, const int* in_sizes, int n_in,
                              void* d_out, int out_size, void* d_ws,
                              size_t ws_size, hipStream_t stream) {
  const float* inputs = (const float*)d_in[0];
  const int* src = (const int*)d_in[1];
  const int* dst = (const int*)d_in[2];
  const float* ew1 = (const float*)d_in[3];
  const float* eg = (const float*)d_in[4];
  const float* eb = (const float*)d_in[5];
  const float* ew2 = (const float*)d_in[6];
  const float* gfc = (const float*)d_in[7];
  const float* gal = (const float*)d_in[8];
  const float* gar = (const float*)d_in[9];
  const float* gb = (const float*)d_in[10];
  const float* dw1 = (const float*)d_in[11];
  const float* dg = (const float*)d_in[12];
  const float* db = (const float*)d_in[13];
  const float* dw2 = (const float*)d_in[14];
  float* out = (float*)d_out;

  // ---- workspace layout (~78 MB) ----
  char* p = (char*)d_ws;
  float* h1 = (float*)p;            p += (size_t)NN * 128 * 4;   // 25.6MB
  float* ybuf = (float*)p;                                        // MLP phases
  _Float16* feat0h = (_Float16*)p;                                // GAT phase
  _Float16* feat1h = feat0h + (size_t)NN * 128;
  p += (size_t)NN * 128 * 4;
  _Float16* h1h = (_Float16*)p;     p += (size_t)NN * 128 * 2;   // 12.8MB
  float* el0 = (float*)p;           p += (size_t)NN * NHEAD * 4;
  float* er0 = (float*)p;           p += (size_t)NN * NHEAD * 4;
  float* el1 = (float*)p;           p += (size_t)NN * NHEAD * 4;
  float* er1 = (float*)p;           p += (size_t)NN * NHEAD * 4;
  float* stats = (float*)p;         p += 1024 * 4;  // stats_e | stats_d
  float* stats_e = stats;
  float* stats_d = stats + 512;
  _Float16* ew1t = (_Float16*)p;    p += (size_t)64 * 128 * 2;
  _Float16* ew2t = (_Float16*)p;    p += (size_t)128 * 128 * 2;
  _Float16* dw1t = (_Float16*)p;    p += (size_t)128 * 128 * 2;
  _Float16* dw2t = (_Float16*)p;    p += (size_t)32 * 128 * 2;
  _Float16* bt = (_Float16*)p;      p += (size_t)4 * 288 * 128 * 2;
  int* rowptr = (int*)p;            p += (size_t)2 * (NN + 1) * 4;
  unsigned short* csr = (unsigned short*)p;   p += (size_t)2 * EE * 2;
  unsigned short* rank = (unsigned short*)p;  p += (size_t)2 * EE * 2;
  int* cnt = (int*)p;               p += (size_t)2 * NN * 4;
  unsigned* elmaxAll = (unsigned*)p; p += 64 * 4;   // 4 layers x 16
  int* segsum = (int*)p;            // 512 ints

  const int GB = (NN + 127) / 128;  // 391

  // ---- fused cooperative build: zero + weights + full CSR chain ----
  {
    BuildArgs ba;
    ba.src = src; ba.dst = dst; ba.cnt = cnt; ba.rank = rank;
    ba.rowptr = rowptr; ba.csr = csr; ba.segsum = segsum;
    ba.elmax = elmaxAll; ba.stats = stats;
    ba.ew1 = ew1; ba.ew2 = ew2; ba.dw1 = dw1; ba.dw2 = dw2;
    ba.gfc = gfc; ba.gal = gal; ba.gar = gar;
    ba.ew1t = ew1t; ba.ew2t = ew2t; ba.dw1t = dw1t; ba.dw2t = dw2t; ba.bt = bt;
    void* kargs[] = {&ba};
    hipLaunchCooperativeKernel((void*)fused_build_k, dim3(CGB), dim3(256),
                               kargs, 0, stream);
  }

  // ---- embed MLP: y = x@w1 (+stats); h1 = relu(bn(y))@w2 + relu(bn(y)) ----
  mfma_gemm_k<64, 128, float, false, false, true, false, true>
      <<<GB, 256, 0, stream>>>(inputs, ew1t, nullptr, nullptr, nullptr,
                               stats_e, nullptr, nullptr, ybuf, NN);
  mfma_gemm_k<128, 128, float, true, true, false, true, true>
      <<<GB, 256, 0, stream>>>(ybuf, ew2t, stats_e, eg, eb, nullptr, ybuf,
                               h1h, h1, NN);

  // ---- 4 GAT layers: merged GEMM(+el/er/elmax) then aggregate ----
  for (int l = 0; l < 4; ++l) {
    unsigned* elm = elmaxAll + l * 16;
    feat_gemm_k<<<GB, 256, 0, stream>>>(
        h1h, bt + (size_t)l * 288 * 128, feat0h, feat1h,
        el0, er0, el1, er1, elm, NN);
    gat_agg_k<<<(NN + 3) / 4, 256, 0, stream>>>(
        (const __half2*)feat0h, (const __half2*)feat1h, el0, er0, el1, er1,
        rowptr, csr, gb + (size_t)(l * 2 + 0) * 128,
        gb + (size_t)(l * 2 + 1) * 128, elm, h1, h1h);
  }

  // ---- decision MLP: y = h1@dw1 (+stats); out = relu(bn(y)) @ dw2 ----
  mfma_gemm_k<128, 128, _Float16, false, false, true, false, true>
      <<<GB, 256, 0, stream>>>(h1h, dw1t, nullptr, nullptr, nullptr, stats_d,
                               nullptr, nullptr, ybuf, NN);
  mfma_gemm_k<128, 32, float, true, false, false, false, true>
      <<<GB, 256, 0, stream>>>(ybuf, dw2t, stats_d, dg, db, nullptr, nullptr,
                               nullptr, out, NN);
}

// Round 11
// 894.188 us; speedup vs baseline: 1.6256x; 1.6256x over previous
//
#include <hip/hip_runtime.h>
#include <hip/hip_fp16.h>
#include <math.h>

#define NN 50000
#define EE 800000
#define NHEAD 8
#define BN_EPS 1e-5f

typedef _Float16 half8_t __attribute__((ext_vector_type(8)));
typedef float float4_t __attribute__((ext_vector_type(4)));

// monotone float<->uint encoding for atomicMax on signed floats
__device__ __forceinline__ unsigned fenc(float f) {
  unsigned u = __float_as_uint(f);
  return (u & 0x80000000u) ? ~u : (u | 0x80000000u);
}
__device__ __forceinline__ float fdec(unsigned k) {
  return (k & 0x80000000u) ? __uint_as_float(k & 0x7fffffffu)
                           : __uint_as_float(~k);
}

// bn scale/shift from raw sums (stats[c]=sum, stats[128+c]=sumsq)
__device__ __forceinline__ void bn_coef(const float* __restrict__ stats,
                                        const float* __restrict__ gamma,
                                        const float* __restrict__ beta,
                                        int c, float& sc, float& sh) {
  float mean = stats[c] * (1.f / NN);
  float var = fmaxf(stats[128 + c] * (1.f / NN) - mean * mean, 0.f);
  sc = gamma[c] * rsqrtf(var + BN_EPS);
  sh = beta[c] - mean * sc;
}

// ---------------------------------------------------------------------------
// MFMA GEMM for embed/decision MLPs (unchanged from R9).
// ---------------------------------------------------------------------------
template <int KDIM, int NC, typename AT, bool ABN, bool RESIDBN, bool STATS,
          bool F16OUT, bool F32OUT>
__global__ __launch_bounds__(256)
void mfma_gemm_k(const AT* __restrict__ A, const _Float16* __restrict__ Bt,
                 const float* __restrict__ bn, const float* __restrict__ gamma,
                 const float* __restrict__ beta, float* __restrict__ statsOut,
                 const float* __restrict__ residf, _Float16* __restrict__ Ch,
                 float* __restrict__ Cf, int M) {
  constexpr int NT = NC / 16;
  const int lane = threadIdx.x & 63, wave = threadIdx.x >> 6;
  const int q = lane >> 4, l16 = lane & 15;
  const int row0 = blockIdx.x * 128 + wave * 32;
  float4_t acc[2][NT];
#pragma unroll
  for (int i = 0; i < 2; ++i)
#pragma unroll
    for (int j = 0; j < NT; ++j) acc[i][j] = (float4_t){0.f, 0.f, 0.f, 0.f};

#pragma unroll
  for (int kk = 0; kk < KDIM / 32; ++kk) {
    float scv[8], shv[8];
    if constexpr (ABN) {
      int kb = kk * 32 + q * 8;
#pragma unroll
      for (int x = 0; x < 8; ++x) bn_coef(bn, gamma, beta, kb + x, scv[x], shv[x]);
    }
    half8_t a[2];
#pragma unroll
    for (int i = 0; i < 2; ++i) {
      int r = row0 + i * 16 + l16;
      r = (r < M) ? r : (M - 1);
      if constexpr (__is_same(AT, _Float16)) {
        a[i] = *(const half8_t*)(A + (size_t)r * KDIM + kk * 32 + q * 8);
      } else {
        const float* ap = (const float*)A + (size_t)r * KDIM + kk * 32 + q * 8;
        float4 v0 = *(const float4*)ap, v1 = *(const float4*)(ap + 4);
        float t[8] = {v0.x, v0.y, v0.z, v0.w, v1.x, v1.y, v1.z, v1.w};
        if constexpr (ABN) {
#pragma unroll
          for (int x = 0; x < 8; ++x) t[x] = fmaxf(t[x] * scv[x] + shv[x], 0.f);
        }
        half8_t hv;
#pragma unroll
        for (int x = 0; x < 8; ++x) hv[x] = (_Float16)t[x];
        a[i] = hv;
      }
    }
#pragma unroll
    for (int j = 0; j < NT; ++j) {
      half8_t b = *(const half8_t*)(Bt + (size_t)(j * 16 + l16) * KDIM + kk * 32 + q * 8);
      acc[0][j] = __builtin_amdgcn_mfma_f32_16x16x32_f16(a[0], b, acc[0][j], 0, 0, 0);
      acc[1][j] = __builtin_amdgcn_mfma_f32_16x16x32_f16(a[1], b, acc[1][j], 0, 0, 0);
    }
  }

  float rsc[NT], rsh[NT];
  if constexpr (RESIDBN) {
#pragma unroll
    for (int j = 0; j < NT; ++j) bn_coef(bn, gamma, beta, j * 16 + l16, rsc[j], rsh[j]);
  }
#pragma unroll
  for (int i = 0; i < 2; ++i)
#pragma unroll
    for (int j = 0; j < NT; ++j)
#pragma unroll
      for (int r = 0; r < 4; ++r) {
        int row = row0 + i * 16 + q * 4 + r;   // C/D: col=lane&15, row=q*4+reg
        if (row >= M) continue;
        int col = j * 16 + l16;
        float v = acc[i][j][r];
        if constexpr (RESIDBN) {
          float rv = residf[(size_t)row * NC + col];
          v += fmaxf(rv * rsc[j] + rsh[j], 0.f);
        }
        if constexpr (F32OUT) Cf[(size_t)row * NC + col] = v;
        if constexpr (F16OUT) Ch[(size_t)row * NC + col] = (_Float16)v;
      }

  if constexpr (STATS) {
    float sc_[NT], sq_[NT];
#pragma unroll
    for (int j = 0; j < NT; ++j) {
      float s = 0.f, qq = 0.f;
#pragma unroll
      for (int i = 0; i < 2; ++i)
#pragma unroll
        for (int r = 0; r < 4; ++r) {
          int row = row0 + i * 16 + q * 4 + r;
          float x = (row < M) ? acc[i][j][r] : 0.f;
          s += x; qq += x * x;
        }
      sc_[j] = s; sq_[j] = qq;
    }
#pragma unroll
    for (int j = 0; j < NT; ++j) {
      sc_[j] += __shfl_xor(sc_[j], 16, 64);
      sq_[j] += __shfl_xor(sq_[j], 16, 64);
      sc_[j] += __shfl_xor(sc_[j], 32, 64);
      sq_[j] += __shfl_xor(sq_[j], 32, 64);
    }
    if (lane < 16) {
#pragma unroll
      for (int j = 0; j < NT; ++j) {
        atomicAdd(&statsOut[j * 16 + l16], sc_[j]);
        atomicAdd(&statsOut[128 + j * 16 + l16], sq_[j]);
      }
    }
  }
}

// ---------------------------------------------------------------------------
// Merged per-layer GAT GEMM, NC=288 (unchanged from R9).
// ---------------------------------------------------------------------------
__global__ __launch_bounds__(256)
void feat_gemm_k(const _Float16* __restrict__ A, const _Float16* __restrict__ Bt,
                 _Float16* __restrict__ feat0, _Float16* __restrict__ feat1,
                 float* __restrict__ el0, float* __restrict__ er0,
                 float* __restrict__ el1, float* __restrict__ er1,
                 unsigned* __restrict__ elmax, int M) {
  constexpr int NT = 18;
  const int lane = threadIdx.x & 63, wave = threadIdx.x >> 6;
  const int q = lane >> 4, l16 = lane & 15;
  const int row0 = blockIdx.x * 128 + wave * 32;
  float4_t acc[2][NT];
#pragma unroll
  for (int i = 0; i < 2; ++i)
#pragma unroll
    for (int j = 0; j < NT; ++j) acc[i][j] = (float4_t){0.f, 0.f, 0.f, 0.f};

#pragma unroll
  for (int kk = 0; kk < 4; ++kk) {
    half8_t a[2];
#pragma unroll
    for (int i = 0; i < 2; ++i) {
      int r = row0 + i * 16 + l16;
      r = (r < M) ? r : (M - 1);
      a[i] = *(const half8_t*)(A + (size_t)r * 128 + kk * 32 + q * 8);
    }
#pragma unroll
    for (int j = 0; j < NT; ++j) {
      half8_t b = *(const half8_t*)(Bt + (size_t)(j * 16 + l16) * 128 + kk * 32 + q * 8);
      acc[0][j] = __builtin_amdgcn_mfma_f32_16x16x32_f16(a[0], b, acc[0][j], 0, 0, 0);
      acc[1][j] = __builtin_amdgcn_mfma_f32_16x16x32_f16(a[1], b, acc[1][j], 0, 0, 0);
    }
  }

#pragma unroll
  for (int i = 0; i < 2; ++i)
#pragma unroll
    for (int r = 0; r < 4; ++r) {
      int row = row0 + i * 16 + q * 4 + r;
      if (row >= M) continue;
#pragma unroll
      for (int j = 0; j < 16; ++j) {
        float v = acc[i][j][r];
        if (j < 8)
          feat0[(size_t)row * 128 + j * 16 + l16] = (_Float16)v;
        else
          feat1[(size_t)row * 128 + (j - 8) * 16 + l16] = (_Float16)v;
      }
      {
        float v = acc[i][16][r];
        if (l16 < 8) el0[(size_t)row * 8 + l16] = v;
        else         er0[(size_t)row * 8 + (l16 - 8)] = v;
        v = acc[i][17][r];
        if (l16 < 8) el1[(size_t)row * 8 + l16] = v;
        else         er1[(size_t)row * 8 + (l16 - 8)] = v;
      }
    }

  float m0 = -1e30f, m1 = -1e30f;
#pragma unroll
  for (int i = 0; i < 2; ++i)
#pragma unroll
    for (int r = 0; r < 4; ++r) {
      m0 = fmaxf(m0, acc[i][16][r]);
      m1 = fmaxf(m1, acc[i][17][r]);
    }
  m0 = fmaxf(m0, __shfl_xor(m0, 16, 64)); m0 = fmaxf(m0, __shfl_xor(m0, 32, 64));
  m1 = fmaxf(m1, __shfl_xor(m1, 16, 64)); m1 = fmaxf(m1, __shfl_xor(m1, 32, 64));
  if (q == 0 && l16 < 8) {
    atomicMax(&elmax[l16], fenc(m0));
    atomicMax(&elmax[8 + l16], fenc(m1));
  }
}

// ---------------------------------------------------------------------------
// Build: weight transposes + merged Bt + zero cnt/elmax/stats (replaces the
// memset dispatch). Plain kernel, 16 blocks — NO cooperative sync (R10 showed
// grid.sync() costs ~130us each on this part).
// ---------------------------------------------------------------------------
__global__ __launch_bounds__(256)
void build_k(const float* __restrict__ ew1, const float* __restrict__ ew2,
             const float* __restrict__ dw1, const float* __restrict__ dw2,
             const float* __restrict__ gfc, const float* __restrict__ gal,
             const float* __restrict__ gar, _Float16* __restrict__ ew1t,
             _Float16* __restrict__ ew2t, _Float16* __restrict__ dw1t,
             _Float16* __restrict__ dw2t, _Float16* __restrict__ bt,
             float* __restrict__ statsz, int* __restrict__ cnt,
             unsigned* __restrict__ elmax) {
  int b = blockIdx.x;
  if (b < 4) {  // layer b merged Bt [288][128]
    _Float16* dst = bt + (size_t)b * 288 * 128;
    for (int idx = threadIdx.x; idx < 288 * 128; idx += 256) {
      int c = idx >> 7, k = idx & 127;
      float v;
      if (c < 128) {
        v = gfc[(size_t)(2 * b) * 16384 + k * 128 + c];
      } else if (c < 256) {
        v = gfc[(size_t)(2 * b + 1) * 16384 + k * 128 + (c - 128)];
      } else {
        int sub = c - 256, blk = sub >> 3, h = sub & 7;
        int r = blk >> 1;
        const float* attn = (blk & 1) ? gar : gal;
        const float* W = gfc + (size_t)(2 * b + r) * 16384;
        const float* av = attn + (size_t)(2 * b + r) * 128 + h * 16;
        float s = 0.f;
#pragma unroll
        for (int d = 0; d < 16; ++d) s += W[k * 128 + h * 16 + d] * av[d];
        v = s;
      }
      dst[idx] = (_Float16)v;  // idx == c*128 + k
    }
  } else if (b < 8) {
    int j = b - 4;
    const float* srcs[4] = {ew1, ew2, dw1, dw2};
    _Float16* dsts[4] = {ew1t, ew2t, dw1t, dw2t};
    const int ks[4] = {64, 128, 128, 128}, ns[4] = {128, 128, 128, 32};
    int k = ks[j], nn = ns[j], total = k * nn;
    for (int i = threadIdx.x; i < total; i += 256) {
      int kk = i / nn, cc = i % nn;
      dsts[j][(size_t)cc * k + kk] = (_Float16)srcs[j][i];
    }
  } else {
    int j = b - 8;  // 8 blocks zero cnt; block 8 also elmax + stats
    for (int i = j * 256 + threadIdx.x; i < 2 * NN; i += 8 * 256) cnt[i] = 0;
    if (j == 0) {
      if (threadIdx.x < 64) elmax[threadIdx.x] = 0u;
      for (int i = threadIdx.x; i < 1024; i += 256) statsz[i] = 0.f;
    }
  }
}

// ---------------------------------------------------------------------------
// CSR build: rank in hist; atomic-free uint16 fill (unchanged from R9).
// ---------------------------------------------------------------------------
__global__ __launch_bounds__(256)
void hist_rank_k(const int* __restrict__ dst, int* __restrict__ cnt,
                 unsigned short* __restrict__ rank) {
  int e = blockIdx.x * 256 + threadIdx.x;
  if (e < 2 * EE) {
    int idx = ((e >= EE) ? NN : 0) + dst[e];
    rank[e] = (unsigned short)atomicAdd(&cnt[idx], 1);
  }
}

__global__ __launch_bounds__(256)
void scan_block_k(const int* __restrict__ in, int* __restrict__ out,
                  int* __restrict__ bsums, int n) {
  in += (size_t)blockIdx.y * n;
  out += (size_t)blockIdx.y * (n + 1);
  bsums += (size_t)blockIdx.y * 256;
  __shared__ int sh[256];
  int i = blockIdx.x * 256 + threadIdx.x;
  int v = (i < n) ? in[i] : 0;
  sh[threadIdx.x] = v;
  __syncthreads();
#pragma unroll
  for (int off = 1; off < 256; off <<= 1) {
    int t = (threadIdx.x >= off) ? sh[threadIdx.x - off] : 0;
    __syncthreads();
    sh[threadIdx.x] += t;
    __syncthreads();
  }
  if (i < n) out[i] = sh[threadIdx.x] - v;  // exclusive
  if (threadIdx.x == 255) bsums[blockIdx.x] = sh[255];
}

__global__ __launch_bounds__(256)
void add_off_k(int* __restrict__ out, const int* __restrict__ bsums, int n) {
  out += (size_t)blockIdx.y * (n + 1);
  bsums += (size_t)blockIdx.y * 256;
  __shared__ int sh[256];
  int b = (threadIdx.x < blockIdx.x) ? bsums[threadIdx.x] : 0;
  sh[threadIdx.x] = b;
  __syncthreads();
#pragma unroll
  for (int off = 128; off >= 1; off >>= 1) {
    if (threadIdx.x < off) sh[threadIdx.x] += sh[threadIdx.x + off];
    __syncthreads();
  }
  int pre = sh[0];
  int i = blockIdx.x * 256 + threadIdx.x;
  if (i < n) out[i] += pre;
  if (i == 0) out[n] = EE;
}

__global__ __launch_bounds__(256)
void fill_k(const int* __restrict__ src, const int* __restrict__ dst,
            const int* __restrict__ rowptr, const unsigned short* __restrict__ rank,
            unsigned short* __restrict__ csr) {
  int e = blockIdx.x * 256 + threadIdx.x;
  if (e >= 2 * EE) return;
  int r = (e >= EE) ? 1 : 0;
  int d = dst[e];
  const int* rp = rowptr + (size_t)r * (NN + 1);
  int p = rp[d] + (int)rank[e];
  csr[(size_t)r * EE + p] = (unsigned short)src[e];
}

// ---------------------------------------------------------------------------
// GAT aggregate: BOTH relations interleaved in one branch-free loop so 16
// feat gathers (4.6KB/wave) are in flight per iteration (R9 had 8). Lane-
// specialized bound-shift softmax (exact); all gather indices clamp-guarded
// (empty/exhausted rows -> valid data, p=0 masks; no NaN path).
// ---------------------------------------------------------------------------
__global__ __launch_bounds__(256)
void gat_agg_k(const __half2* __restrict__ f0, const __half2* __restrict__ f1,
               const float* __restrict__ el0, const float* __restrict__ er0,
               const float* __restrict__ el1, const float* __restrict__ er1,
               const int* __restrict__ rowptr, const unsigned short* __restrict__ csr,
               const float* __restrict__ b0, const float* __restrict__ b1,
               const unsigned* __restrict__ elmax,
               float* __restrict__ h1, _Float16* __restrict__ h1h) {
  int n = blockIdx.x * 4 + (threadIdx.x >> 6);
  if (n >= NN) return;
  int lane = threadIdx.x & 63;
  int head = lane >> 3, eslot = lane & 7;
  float er0h = er0[(size_t)n * 8 + head];
  float er1h = er1[(size_t)n * 8 + head];
  float bnd0 = fdec(elmax[head]) + er0h;       bnd0 = fmaxf(bnd0, 0.2f * bnd0);
  float bnd1 = fdec(elmax[8 + head]) + er1h;   bnd1 = fmaxf(bnd1, 0.2f * bnd1);
  int beg0 = rowptr[n], end0 = rowptr[n + 1];
  const int* rp1 = rowptr + (NN + 1);
  int beg1 = rp1[n], end1 = rp1[n + 1];
  const unsigned short* csr1 = csr + EE;
  int len = max(end0 - beg0, end1 - beg1);

  float ls0 = 0.f, a00 = 0.f, a01 = 0.f;
  float ls1 = 0.f, a10 = 0.f, a11 = 0.f;
  for (int t = 0; t < len; t += 8) {
    int t0 = beg0 + t, t1 = beg1 + t;
    // clamp-guarded csr loads (wave-uniform addresses -> broadcast)
    int s0[8], s1[8];
#pragma unroll
    for (int j = 0; j < 8; ++j) {
      s0[j] = (int)csr[max(min(t0 + j, end0 - 1), 0)];
      s1[j] = (int)csr1[max(min(t1 + j, end1 - 1), 0)];
    }
    // own-slot el for lane-specialized softmax chains
    int so0 = (int)csr[max(min(t0 + eslot, end0 - 1), 0)];
    int so1 = (int)csr1[max(min(t1 + eslot, end1 - 1), 0)];
    float ev0 = el0[(size_t)so0 * 8 + head];
    float ev1 = el1[(size_t)so1 * 8 + head];
    // 16 feat gathers in flight
    __half2 g0[8], g1[8];
#pragma unroll
    for (int j = 0; j < 8; ++j) {
      g0[j] = f0[(size_t)s0[j] * 64 + lane];
      g1[j] = f1[(size_t)s1[j] * 64 + lane];
    }
    // softmax chains (one exp per relation per 8-edge batch per lane)
    float e0 = ev0 + er0h; e0 = fmaxf(e0, 0.2f * e0);
    float p0 = __expf(e0 - bnd0);
    p0 = (t0 + eslot < end0) ? p0 : 0.f;
    float e1 = ev1 + er1h; e1 = fmaxf(e1, 0.2f * e1);
    float p1 = __expf(e1 - bnd1);
    p1 = (t1 + eslot < end1) ? p1 : 0.f;
#pragma unroll
    for (int j = 0; j < 8; ++j) {
      float pj0 = __shfl(p0, (lane & 56) | j);
      float pj1 = __shfl(p1, (lane & 56) | j);
      float2 v0 = __half22float2(g0[j]);
      float2 v1 = __half22float2(g1[j]);
      ls0 += pj0; a00 += pj0 * v0.x; a01 += pj0 * v0.y;
      ls1 += pj1; a10 += pj1 * v1.x; a11 += pj1 * v1.y;
    }
  }
  float inv0 = (ls0 > 0.f) ? 1.f / ls0 : 0.f;  // isolated node -> rst = 0
  float inv1 = (ls1 > 0.f) ? 1.f / ls1 : 0.f;
  float t0 = a00 * inv0 + a10 * inv1 + b0[lane * 2] + b1[lane * 2];
  float t1 = a01 * inv0 + a11 * inv1 + b0[lane * 2 + 1] + b1[lane * 2 + 1];
  t0 = (t0 > 0.f) ? t0 : 0.01f * t0;           // leaky_relu 0.01
  t1 = (t1 > 0.f) ? t1 : 0.01f * t1;
  float2* h2p = (float2*)h1 + (size_t)n * 64 + lane;
  float2 h = *h2p;
  h.x += t0; h.y += t1;
  *h2p = h;
  __half2* hh = (__half2*)h1h + (size_t)n * 64 + lane;
  *hh = __floats2half2_rn(h.x, h.y);
}

// ---------------------------------------------------------------------------
extern "C" void kernel_launch(void* const* d_in, const int* in_sizes, int n_in,
                              void* d_out, int out_size, void* d_ws,
                              size_t ws_size, hipStream_t stream) {
  const float* inputs = (const float*)d_in[0];
  const int* src = (const int*)d_in[1];
  const int* dst = (const int*)d_in[2];
  const float* ew1 = (const float*)d_in[3];
  const float* eg = (const float*)d_in[4];
  const float* eb = (const float*)d_in[5];
  const float* ew2 = (const float*)d_in[6];
  const float* gfc = (const float*)d_in[7];
  const float* gal = (const float*)d_in[8];
  const float* gar = (const float*)d_in[9];
  const float* gb = (const float*)d_in[10];
  const float* dw1 = (const float*)d_in[11];
  const float* dg = (const float*)d_in[12];
  const float* db = (const float*)d_in[13];
  const float* dw2 = (const float*)d_in[14];
  float* out = (float*)d_out;

  // ---- workspace layout (~78 MB) ----
  char* p = (char*)d_ws;
  float* h1 = (float*)p;            p += (size_t)NN * 128 * 4;   // 25.6MB
  float* ybuf = (float*)p;                                        // MLP phases
  _Float16* feat0h = (_Float16*)p;                                // GAT phase
  _Float16* feat1h = feat0h + (size_t)NN * 128;
  p += (size_t)NN * 128 * 4;
  _Float16* h1h = (_Float16*)p;     p += (size_t)NN * 128 * 2;   // 12.8MB
  float* el0 = (float*)p;           p += (size_t)NN * NHEAD * 4;
  float* er0 = (float*)p;           p += (size_t)NN * NHEAD * 4;
  float* el1 = (float*)p;           p += (size_t)NN * NHEAD * 4;
  float* er1 = (float*)p;           p += (size_t)NN * NHEAD * 4;
  float* stats = (float*)p;         p += 1024 * 4;  // stats_e | stats_d
  float* stats_e = stats;
  float* stats_d = stats + 512;
  _Float16* ew1t = (_Float16*)p;    p += (size_t)64 * 128 * 2;
  _Float16* ew2t = (_Float16*)p;    p += (size_t)128 * 128 * 2;
  _Float16* dw1t = (_Float16*)p;    p += (size_t)128 * 128 * 2;
  _Float16* dw2t = (_Float16*)p;    p += (size_t)32 * 128 * 2;
  _Float16* bt = (_Float16*)p;      p += (size_t)4 * 288 * 128 * 2;
  int* rowptr = (int*)p;            p += (size_t)2 * (NN + 1) * 4;
  unsigned short* csr = (unsigned short*)p;   p += (size_t)2 * EE * 2;
  unsigned short* rank = (unsigned short*)p;  p += (size_t)2 * EE * 2;
  int* cnt = (int*)p;               p += (size_t)2 * NN * 4;
  unsigned* elmaxAll = (unsigned*)p; p += 64 * 4;   // 4 layers x 16
  int* bsums = (int*)p;             // 2x256 ints

  const int SCB = (NN + 255) / 256;        // 196
  const int EGB2 = (2 * EE + 255) / 256;   // 6250
  const int GB = (NN + 127) / 128;         // 391

  // ---- build (weights + zero cnt/elmax/stats), then CSR chain ----
  build_k<<<16, 256, 0, stream>>>(ew1, ew2, dw1, dw2, gfc, gal, gar,
                                  ew1t, ew2t, dw1t, dw2t, bt, stats,
                                  cnt, elmaxAll);
  hist_rank_k<<<EGB2, 256, 0, stream>>>(dst, cnt, rank);
  scan_block_k<<<dim3(SCB, 2), 256, 0, stream>>>(cnt, rowptr, bsums, NN);
  add_off_k<<<dim3(SCB, 2), 256, 0, stream>>>(rowptr, bsums, NN);
  fill_k<<<EGB2, 256, 0, stream>>>(src, dst, rowptr, rank, csr);

  // ---- embed MLP: y = x@w1 (+stats); h1 = relu(bn(y))@w2 + relu(bn(y)) ----
  mfma_gemm_k<64, 128, float, false, false, true, false, true>
      <<<GB, 256, 0, stream>>>(inputs, ew1t, nullptr, nullptr, nullptr,
                               stats_e, nullptr, nullptr, ybuf, NN);
  mfma_gemm_k<128, 128, float, true, true, false, true, true>
      <<<GB, 256, 0, stream>>>(ybuf, ew2t, stats_e, eg, eb, nullptr, ybuf,
                               h1h, h1, NN);

  // ---- 4 GAT layers: merged GEMM(+el/er/elmax) then aggregate ----
  for (int l = 0; l < 4; ++l) {
    unsigned* elm = elmaxAll + l * 16;
    feat_gemm_k<<<GB, 256, 0, stream>>>(
        h1h, bt + (size_t)l * 288 * 128, feat0h, feat1h,
        el0, er0, el1, er1, elm, NN);
    gat_agg_k<<<(NN + 3) / 4, 256, 0, stream>>>(
        (const __half2*)feat0h, (const __half2*)feat1h, el0, er0, el1, er1,
        rowptr, csr, gb + (size_t)(l * 2 + 0) * 128,
        gb + (size_t)(l * 2 + 1) * 128, elm, h1, h1h);
  }

  // ---- decision MLP: y = h1@dw1 (+stats); out = relu(bn(y)) @ dw2 ----
  mfma_gemm_k<128, 128, _Float16, false, false, true, false, true>
      <<<GB, 256, 0, stream>>>(h1h, dw1t, nullptr, nullptr, nullptr, stats_d,
                               nullptr, nullptr, ybuf, NN);
  mfma_gemm_k<128, 32, float, true, false, false, false, true>
      <<<GB, 256, 0, stream>>>(ybuf, dw2t, stats_d, dg, db, nullptr, nullptr,
                               nullptr, out, NN);
}

// Round 12
// 864.347 us; speedup vs baseline: 1.6818x; 1.0345x over previous
//
#include <hip/hip_runtime.h>
#include <hip/hip_fp16.h>
#include <math.h>

#define NN 50000
#define EE 800000
#define NHEAD 8
#define BN_EPS 1e-5f

typedef _Float16 half8_t __attribute__((ext_vector_type(8)));
typedef float float4_t __attribute__((ext_vector_type(4)));

// monotone float<->uint encoding for atomicMax on signed floats
__device__ __forceinline__ unsigned fenc(float f) {
  unsigned u = __float_as_uint(f);
  return (u & 0x80000000u) ? ~u : (u | 0x80000000u);
}
__device__ __forceinline__ float fdec(unsigned k) {
  return (k & 0x80000000u) ? __uint_as_float(k & 0x7fffffffu)
                           : __uint_as_float(~k);
}

// bn scale/shift from raw sums (stats[c]=sum, stats[128+c]=sumsq)
__device__ __forceinline__ void bn_coef(const float* __restrict__ stats,
                                        const float* __restrict__ gamma,
                                        const float* __restrict__ beta,
                                        int c, float& sc, float& sh) {
  float mean = stats[c] * (1.f / NN);
  float var = fmaxf(stats[128 + c] * (1.f / NN) - mean * mean, 0.f);
  sc = gamma[c] * rsqrtf(var + BN_EPS);
  sh = beta[c] - mean * sc;
}

// ---------------------------------------------------------------------------
// MFMA GEMM for embed/decision MLPs. ABN now supports fp16 A (load, cvt,
// bn+relu, cvt back). RESIDBN reads fp16 residual. BN stats accumulate from
// fp32 MFMA accumulators (storage rounding does not affect mean/var).
// ---------------------------------------------------------------------------
template <int KDIM, int NC, typename AT, bool ABN, bool RESIDBN, bool STATS,
          bool F16OUT, bool F32OUT>
__global__ __launch_bounds__(256)
void mfma_gemm_k(const AT* __restrict__ A, const _Float16* __restrict__ Bt,
                 const float* __restrict__ bn, const float* __restrict__ gamma,
                 const float* __restrict__ beta, float* __restrict__ statsOut,
                 const _Float16* __restrict__ residh, _Float16* __restrict__ Ch,
                 float* __restrict__ Cf, int M) {
  constexpr int NT = NC / 16;
  const int lane = threadIdx.x & 63, wave = threadIdx.x >> 6;
  const int q = lane >> 4, l16 = lane & 15;
  const int row0 = blockIdx.x * 128 + wave * 32;
  float4_t acc[2][NT];
#pragma unroll
  for (int i = 0; i < 2; ++i)
#pragma unroll
    for (int j = 0; j < NT; ++j) acc[i][j] = (float4_t){0.f, 0.f, 0.f, 0.f};

#pragma unroll
  for (int kk = 0; kk < KDIM / 32; ++kk) {
    float scv[8], shv[8];
    if constexpr (ABN) {
      int kb = kk * 32 + q * 8;
#pragma unroll
      for (int x = 0; x < 8; ++x) bn_coef(bn, gamma, beta, kb + x, scv[x], shv[x]);
    }
    half8_t a[2];
#pragma unroll
    for (int i = 0; i < 2; ++i) {
      int r = row0 + i * 16 + l16;
      r = (r < M) ? r : (M - 1);
      if constexpr (__is_same(AT, _Float16)) {
        half8_t hv = *(const half8_t*)(A + (size_t)r * KDIM + kk * 32 + q * 8);
        if constexpr (ABN) {
#pragma unroll
          for (int x = 0; x < 8; ++x)
            hv[x] = (_Float16)fmaxf((float)hv[x] * scv[x] + shv[x], 0.f);
        }
        a[i] = hv;
      } else {
        const float* ap = (const float*)A + (size_t)r * KDIM + kk * 32 + q * 8;
        float4 v0 = *(const float4*)ap, v1 = *(const float4*)(ap + 4);
        float t[8] = {v0.x, v0.y, v0.z, v0.w, v1.x, v1.y, v1.z, v1.w};
        if constexpr (ABN) {
#pragma unroll
          for (int x = 0; x < 8; ++x) t[x] = fmaxf(t[x] * scv[x] + shv[x], 0.f);
        }
        half8_t hv;
#pragma unroll
        for (int x = 0; x < 8; ++x) hv[x] = (_Float16)t[x];
        a[i] = hv;
      }
    }
#pragma unroll
    for (int j = 0; j < NT; ++j) {
      half8_t b = *(const half8_t*)(Bt + (size_t)(j * 16 + l16) * KDIM + kk * 32 + q * 8);
      acc[0][j] = __builtin_amdgcn_mfma_f32_16x16x32_f16(a[0], b, acc[0][j], 0, 0, 0);
      acc[1][j] = __builtin_amdgcn_mfma_f32_16x16x32_f16(a[1], b, acc[1][j], 0, 0, 0);
    }
  }

  float rsc[NT], rsh[NT];
  if constexpr (RESIDBN) {
#pragma unroll
    for (int j = 0; j < NT; ++j) bn_coef(bn, gamma, beta, j * 16 + l16, rsc[j], rsh[j]);
  }
#pragma unroll
  for (int i = 0; i < 2; ++i)
#pragma unroll
    for (int j = 0; j < NT; ++j)
#pragma unroll
      for (int r = 0; r < 4; ++r) {
        int row = row0 + i * 16 + q * 4 + r;   // C/D: col=lane&15, row=q*4+reg
        if (row >= M) continue;
        int col = j * 16 + l16;
        float v = acc[i][j][r];
        if constexpr (RESIDBN) {
          float rv = (float)residh[(size_t)row * NC + col];
          v += fmaxf(rv * rsc[j] + rsh[j], 0.f);
        }
        if constexpr (F32OUT) Cf[(size_t)row * NC + col] = v;
        if constexpr (F16OUT) Ch[(size_t)row * NC + col] = (_Float16)v;
      }

  if constexpr (STATS) {
    float sc_[NT], sq_[NT];
#pragma unroll
    for (int j = 0; j < NT; ++j) {
      float s = 0.f, qq = 0.f;
#pragma unroll
      for (int i = 0; i < 2; ++i)
#pragma unroll
        for (int r = 0; r < 4; ++r) {
          int row = row0 + i * 16 + q * 4 + r;
          float x = (row < M) ? acc[i][j][r] : 0.f;
          s += x; qq += x * x;
        }
      sc_[j] = s; sq_[j] = qq;
    }
#pragma unroll
    for (int j = 0; j < NT; ++j) {
      sc_[j] += __shfl_xor(sc_[j], 16, 64);
      sq_[j] += __shfl_xor(sq_[j], 16, 64);
      sc_[j] += __shfl_xor(sc_[j], 32, 64);
      sq_[j] += __shfl_xor(sq_[j], 32, 64);
    }
    if (lane < 16) {
#pragma unroll
      for (int j = 0; j < NT; ++j) {
        atomicAdd(&statsOut[j * 16 + l16], sc_[j]);
        atomicAdd(&statsOut[128 + j * 16 + l16], sq_[j]);
      }
    }
  }
}

// ---------------------------------------------------------------------------
// Merged per-layer GAT GEMM, NC=288 (unchanged from R11).
// ---------------------------------------------------------------------------
__global__ __launch_bounds__(256)
void feat_gemm_k(const _Float16* __restrict__ A, const _Float16* __restrict__ Bt,
                 _Float16* __restrict__ feat0, _Float16* __restrict__ feat1,
                 float* __restrict__ el0, float* __restrict__ er0,
                 float* __restrict__ el1, float* __restrict__ er1,
                 unsigned* __restrict__ elmax, int M) {
  constexpr int NT = 18;
  const int lane = threadIdx.x & 63, wave = threadIdx.x >> 6;
  const int q = lane >> 4, l16 = lane & 15;
  const int row0 = blockIdx.x * 128 + wave * 32;
  float4_t acc[2][NT];
#pragma unroll
  for (int i = 0; i < 2; ++i)
#pragma unroll
    for (int j = 0; j < NT; ++j) acc[i][j] = (float4_t){0.f, 0.f, 0.f, 0.f};

#pragma unroll
  for (int kk = 0; kk < 4; ++kk) {
    half8_t a[2];
#pragma unroll
    for (int i = 0; i < 2; ++i) {
      int r = row0 + i * 16 + l16;
      r = (r < M) ? r : (M - 1);
      a[i] = *(const half8_t*)(A + (size_t)r * 128 + kk * 32 + q * 8);
    }
#pragma unroll
    for (int j = 0; j < NT; ++j) {
      half8_t b = *(const half8_t*)(Bt + (size_t)(j * 16 + l16) * 128 + kk * 32 + q * 8);
      acc[0][j] = __builtin_amdgcn_mfma_f32_16x16x32_f16(a[0], b, acc[0][j], 0, 0, 0);
      acc[1][j] = __builtin_amdgcn_mfma_f32_16x16x32_f16(a[1], b, acc[1][j], 0, 0, 0);
    }
  }

#pragma unroll
  for (int i = 0; i < 2; ++i)
#pragma unroll
    for (int r = 0; r < 4; ++r) {
      int row = row0 + i * 16 + q * 4 + r;
      if (row >= M) continue;
#pragma unroll
      for (int j = 0; j < 16; ++j) {
        float v = acc[i][j][r];
        if (j < 8)
          feat0[(size_t)row * 128 + j * 16 + l16] = (_Float16)v;
        else
          feat1[(size_t)row * 128 + (j - 8) * 16 + l16] = (_Float16)v;
      }
      {
        float v = acc[i][16][r];
        if (l16 < 8) el0[(size_t)row * 8 + l16] = v;
        else         er0[(size_t)row * 8 + (l16 - 8)] = v;
        v = acc[i][17][r];
        if (l16 < 8) el1[(size_t)row * 8 + l16] = v;
        else         er1[(size_t)row * 8 + (l16 - 8)] = v;
      }
    }

  float m0 = -1e30f, m1 = -1e30f;
#pragma unroll
  for (int i = 0; i < 2; ++i)
#pragma unroll
    for (int r = 0; r < 4; ++r) {
      m0 = fmaxf(m0, acc[i][16][r]);
      m1 = fmaxf(m1, acc[i][17][r]);
    }
  m0 = fmaxf(m0, __shfl_xor(m0, 16, 64)); m0 = fmaxf(m0, __shfl_xor(m0, 32, 64));
  m1 = fmaxf(m1, __shfl_xor(m1, 16, 64)); m1 = fmaxf(m1, __shfl_xor(m1, 32, 64));
  if (q == 0 && l16 < 8) {
    atomicMax(&elmax[l16], fenc(m0));
    atomicMax(&elmax[8 + l16], fenc(m1));
  }
}

// ---------------------------------------------------------------------------
// Build: weight transposes + merged Bt + zero cnt/elmax/stats.
// ---------------------------------------------------------------------------
__global__ __launch_bounds__(256)
void build_k(const float* __restrict__ ew1, const float* __restrict__ ew2,
             const float* __restrict__ dw1, const float* __restrict__ dw2,
             const float* __restrict__ gfc, const float* __restrict__ gal,
             const float* __restrict__ gar, _Float16* __restrict__ ew1t,
             _Float16* __restrict__ ew2t, _Float16* __restrict__ dw1t,
             _Float16* __restrict__ dw2t, _Float16* __restrict__ bt,
             float* __restrict__ statsz, int* __restrict__ cnt,
             unsigned* __restrict__ elmax) {
  int b = blockIdx.x;
  if (b < 4) {  // layer b merged Bt [288][128]
    _Float16* dst = bt + (size_t)b * 288 * 128;
    for (int idx = threadIdx.x; idx < 288 * 128; idx += 256) {
      int c = idx >> 7, k = idx & 127;
      float v;
      if (c < 128) {
        v = gfc[(size_t)(2 * b) * 16384 + k * 128 + c];
      } else if (c < 256) {
        v = gfc[(size_t)(2 * b + 1) * 16384 + k * 128 + (c - 128)];
      } else {
        int sub = c - 256, blk = sub >> 3, h = sub & 7;
        int r = blk >> 1;
        const float* attn = (blk & 1) ? gar : gal;
        const float* W = gfc + (size_t)(2 * b + r) * 16384;
        const float* av = attn + (size_t)(2 * b + r) * 128 + h * 16;
        float s = 0.f;
#pragma unroll
        for (int d = 0; d < 16; ++d) s += W[k * 128 + h * 16 + d] * av[d];
        v = s;
      }
      dst[idx] = (_Float16)v;  // idx == c*128 + k
    }
  } else if (b < 8) {
    int j = b - 4;
    const float* srcs[4] = {ew1, ew2, dw1, dw2};
    _Float16* dsts[4] = {ew1t, ew2t, dw1t, dw2t};
    const int ks[4] = {64, 128, 128, 128}, ns[4] = {128, 128, 128, 32};
    int k = ks[j], nn = ns[j], total = k * nn;
    for (int i = threadIdx.x; i < total; i += 256) {
      int kk = i / nn, cc = i % nn;
      dsts[j][(size_t)cc * k + kk] = (_Float16)srcs[j][i];
    }
  } else {
    int j = b - 8;  // 8 blocks zero cnt; block 8 also elmax + stats
    for (int i = j * 256 + threadIdx.x; i < 2 * NN; i += 8 * 256) cnt[i] = 0;
    if (j == 0) {
      if (threadIdx.x < 64) elmax[threadIdx.x] = 0u;
      for (int i = threadIdx.x; i < 1024; i += 256) statsz[i] = 0.f;
    }
  }
}

// ---------------------------------------------------------------------------
// CSR build: rank in hist; atomic-free uint16 fill (unchanged).
// ---------------------------------------------------------------------------
__global__ __launch_bounds__(256)
void hist_rank_k(const int* __restrict__ dst, int* __restrict__ cnt,
                 unsigned short* __restrict__ rank) {
  int e = blockIdx.x * 256 + threadIdx.x;
  if (e < 2 * EE) {
    int idx = ((e >= EE) ? NN : 0) + dst[e];
    rank[e] = (unsigned short)atomicAdd(&cnt[idx], 1);
  }
}

__global__ __launch_bounds__(256)
void scan_block_k(const int* __restrict__ in, int* __restrict__ out,
                  int* __restrict__ bsums, int n) {
  in += (size_t)blockIdx.y * n;
  out += (size_t)blockIdx.y * (n + 1);
  bsums += (size_t)blockIdx.y * 256;
  __shared__ int sh[256];
  int i = blockIdx.x * 256 + threadIdx.x;
  int v = (i < n) ? in[i] : 0;
  sh[threadIdx.x] = v;
  __syncthreads();
#pragma unroll
  for (int off = 1; off < 256; off <<= 1) {
    int t = (threadIdx.x >= off) ? sh[threadIdx.x - off] : 0;
    __syncthreads();
    sh[threadIdx.x] += t;
    __syncthreads();
  }
  if (i < n) out[i] = sh[threadIdx.x] - v;  // exclusive
  if (threadIdx.x == 255) bsums[blockIdx.x] = sh[255];
}

__global__ __launch_bounds__(256)
void add_off_k(int* __restrict__ out, const int* __restrict__ bsums, int n) {
  out += (size_t)blockIdx.y * (n + 1);
  bsums += (size_t)blockIdx.y * 256;
  __shared__ int sh[256];
  int b = (threadIdx.x < blockIdx.x) ? bsums[threadIdx.x] : 0;
  sh[threadIdx.x] = b;
  __syncthreads();
#pragma unroll
  for (int off = 128; off >= 1; off >>= 1) {
    if (threadIdx.x < off) sh[threadIdx.x] += sh[threadIdx.x + off];
    __syncthreads();
  }
  int pre = sh[0];
  int i = blockIdx.x * 256 + threadIdx.x;
  if (i < n) out[i] += pre;
  if (i == 0) out[n] = EE;
}

__global__ __launch_bounds__(256)
void fill_k(const int* __restrict__ src, const int* __restrict__ dst,
            const int* __restrict__ rowptr, const unsigned short* __restrict__ rank,
            unsigned short* __restrict__ csr) {
  int e = blockIdx.x * 256 + threadIdx.x;
  if (e >= 2 * EE) return;
  int r = (e >= EE) ? 1 : 0;
  int d = dst[e];
  const int* rp = rowptr + (size_t)r * (NN + 1);
  int p = rp[d] + (int)rank[e];
  csr[(size_t)r * EE + p] = (unsigned short)src[e];
}

// ---------------------------------------------------------------------------
// GAT aggregate (R11 structure) with fp16-only residual stream: h1h read,
// fp32 register accumulate, h1h write. Saves ~38MB/dispatch vs fp32 h1.
// ---------------------------------------------------------------------------
__global__ __launch_bounds__(256)
void gat_agg_k(const __half2* __restrict__ f0, const __half2* __restrict__ f1,
               const float* __restrict__ el0, const float* __restrict__ er0,
               const float* __restrict__ el1, const float* __restrict__ er1,
               const int* __restrict__ rowptr, const unsigned short* __restrict__ csr,
               const float* __restrict__ b0, const float* __restrict__ b1,
               const unsigned* __restrict__ elmax,
               _Float16* __restrict__ h1h) {
  int n = blockIdx.x * 4 + (threadIdx.x >> 6);
  if (n >= NN) return;
  int lane = threadIdx.x & 63;
  int head = lane >> 3, eslot = lane & 7;
  float er0h = er0[(size_t)n * 8 + head];
  float er1h = er1[(size_t)n * 8 + head];
  float bnd0 = fdec(elmax[head]) + er0h;       bnd0 = fmaxf(bnd0, 0.2f * bnd0);
  float bnd1 = fdec(elmax[8 + head]) + er1h;   bnd1 = fmaxf(bnd1, 0.2f * bnd1);
  int beg0 = rowptr[n], end0 = rowptr[n + 1];
  const int* rp1 = rowptr + (NN + 1);
  int beg1 = rp1[n], end1 = rp1[n + 1];
  const unsigned short* csr1 = csr + EE;
  int len = max(end0 - beg0, end1 - beg1);

  float ls0 = 0.f, a00 = 0.f, a01 = 0.f;
  float ls1 = 0.f, a10 = 0.f, a11 = 0.f;
  for (int t = 0; t < len; t += 8) {
    int t0 = beg0 + t, t1 = beg1 + t;
    int s0[8], s1[8];
#pragma unroll
    for (int j = 0; j < 8; ++j) {
      s0[j] = (int)csr[max(min(t0 + j, end0 - 1), 0)];
      s1[j] = (int)csr1[max(min(t1 + j, end1 - 1), 0)];
    }
    int so0 = (int)csr[max(min(t0 + eslot, end0 - 1), 0)];
    int so1 = (int)csr1[max(min(t1 + eslot, end1 - 1), 0)];
    float ev0 = el0[(size_t)so0 * 8 + head];
    float ev1 = el1[(size_t)so1 * 8 + head];
    __half2 g0[8], g1[8];
#pragma unroll
    for (int j = 0; j < 8; ++j) {
      g0[j] = f0[(size_t)s0[j] * 64 + lane];
      g1[j] = f1[(size_t)s1[j] * 64 + lane];
    }
    float e0 = ev0 + er0h; e0 = fmaxf(e0, 0.2f * e0);
    float p0 = __expf(e0 - bnd0);
    p0 = (t0 + eslot < end0) ? p0 : 0.f;
    float e1 = ev1 + er1h; e1 = fmaxf(e1, 0.2f * e1);
    float p1 = __expf(e1 - bnd1);
    p1 = (t1 + eslot < end1) ? p1 : 0.f;
#pragma unroll
    for (int j = 0; j < 8; ++j) {
      float pj0 = __shfl(p0, (lane & 56) | j);
      float pj1 = __shfl(p1, (lane & 56) | j);
      float2 v0 = __half22float2(g0[j]);
      float2 v1 = __half22float2(g1[j]);
      ls0 += pj0; a00 += pj0 * v0.x; a01 += pj0 * v0.y;
      ls1 += pj1; a10 += pj1 * v1.x; a11 += pj1 * v1.y;
    }
  }
  float inv0 = (ls0 > 0.f) ? 1.f / ls0 : 0.f;  // isolated node -> rst = 0
  float inv1 = (ls1 > 0.f) ? 1.f / ls1 : 0.f;
  float t0 = a00 * inv0 + a10 * inv1 + b0[lane * 2] + b1[lane * 2];
  float t1 = a01 * inv0 + a11 * inv1 + b0[lane * 2 + 1] + b1[lane * 2 + 1];
  t0 = (t0 > 0.f) ? t0 : 0.01f * t0;           // leaky_relu 0.01
  t1 = (t1 > 0.f) ? t1 : 0.01f * t1;
  __half2* hh = (__half2*)h1h + (size_t)n * 64 + lane;
  float2 h = __half22float2(*hh);
  h.x += t0; h.y += t1;
  *hh = __floats2half2_rn(h.x, h.y);
}

// ---------------------------------------------------------------------------
extern "C" void kernel_launch(void* const* d_in, const int* in_sizes, int n_in,
                              void* d_out, int out_size, void* d_ws,
                              size_t ws_size, hipStream_t stream) {
  const float* inputs = (const float*)d_in[0];
  const int* src = (const int*)d_in[1];
  const int* dst = (const int*)d_in[2];
  const float* ew1 = (const float*)d_in[3];
  const float* eg = (const float*)d_in[4];
  const float* eb = (const float*)d_in[5];
  const float* ew2 = (const float*)d_in[6];
  const float* gfc = (const float*)d_in[7];
  const float* gal = (const float*)d_in[8];
  const float* gar = (const float*)d_in[9];
  const float* gb = (const float*)d_in[10];
  const float* dw1 = (const float*)d_in[11];
  const float* dg = (const float*)d_in[12];
  const float* db = (const float*)d_in[13];
  const float* dw2 = (const float*)d_in[14];
  float* out = (float*)d_out;

  // ---- workspace layout (~52 MB) ----
  char* p = (char*)d_ws;
  // region A (25.6MB): ybuf_h (MLP phases) | feat0h+feat1h (GAT phase)
  _Float16* feat0h = (_Float16*)p;
  _Float16* feat1h = feat0h + (size_t)NN * 128;
  _Float16* ybuf_h = feat0h;        // alias: MLP and GAT phases don't overlap
  p += (size_t)NN * 128 * 4;
  _Float16* h1h = (_Float16*)p;     p += (size_t)NN * 128 * 2;   // 12.8MB
  float* el0 = (float*)p;           p += (size_t)NN * NHEAD * 4;
  float* er0 = (float*)p;           p += (size_t)NN * NHEAD * 4;
  float* el1 = (float*)p;           p += (size_t)NN * NHEAD * 4;
  float* er1 = (float*)p;           p += (size_t)NN * NHEAD * 4;
  float* stats = (float*)p;         p += 1024 * 4;  // stats_e | stats_d
  float* stats_e = stats;
  float* stats_d = stats + 512;
  _Float16* ew1t = (_Float16*)p;    p += (size_t)64 * 128 * 2;
  _Float16* ew2t = (_Float16*)p;    p += (size_t)128 * 128 * 2;
  _Float16* dw1t = (_Float16*)p;    p += (size_t)128 * 128 * 2;
  _Float16* dw2t = (_Float16*)p;    p += (size_t)32 * 128 * 2;
  _Float16* bt = (_Float16*)p;      p += (size_t)4 * 288 * 128 * 2;
  int* rowptr = (int*)p;            p += (size_t)2 * (NN + 1) * 4;
  unsigned short* csr = (unsigned short*)p;   p += (size_t)2 * EE * 2;
  unsigned short* rank = (unsigned short*)p;  p += (size_t)2 * EE * 2;
  int* cnt = (int*)p;               p += (size_t)2 * NN * 4;
  unsigned* elmaxAll = (unsigned*)p; p += 64 * 4;   // 4 layers x 16
  int* bsums = (int*)p;             // 2x256 ints

  const int SCB = (NN + 255) / 256;        // 196
  const int EGB2 = (2 * EE + 255) / 256;   // 6250
  const int GB = (NN + 127) / 128;         // 391

  // ---- build (weights + zero cnt/elmax/stats), then CSR chain ----
  build_k<<<16, 256, 0, stream>>>(ew1, ew2, dw1, dw2, gfc, gal, gar,
                                  ew1t, ew2t, dw1t, dw2t, bt, stats,
                                  cnt, elmaxAll);
  hist_rank_k<<<EGB2, 256, 0, stream>>>(dst, cnt, rank);
  scan_block_k<<<dim3(SCB, 2), 256, 0, stream>>>(cnt, rowptr, bsums, NN);
  add_off_k<<<dim3(SCB, 2), 256, 0, stream>>>(rowptr, bsums, NN);
  fill_k<<<EGB2, 256, 0, stream>>>(src, dst, rowptr, rank, csr);

  // ---- embed MLP: y=x@w1 (fp16 store, +stats); h1h=relu(bn(y))@w2+relu(bn(y))
  mfma_gemm_k<64, 128, float, false, false, true, true, false>
      <<<GB, 256, 0, stream>>>(inputs, ew1t, nullptr, nullptr, nullptr,
                               stats_e, nullptr, ybuf_h, nullptr, NN);
  mfma_gemm_k<128, 128, _Float16, true, true, false, true, false>
      <<<GB, 256, 0, stream>>>(ybuf_h, ew2t, stats_e, eg, eb, nullptr,
                               ybuf_h, h1h, nullptr, NN);

  // ---- 4 GAT layers: merged GEMM(+el/er/elmax) then aggregate ----
  for (int l = 0; l < 4; ++l) {
    unsigned* elm = elmaxAll + l * 16;
    feat_gemm_k<<<GB, 256, 0, stream>>>(
        h1h, bt + (size_t)l * 288 * 128, feat0h, feat1h,
        el0, er0, el1, er1, elm, NN);
    gat_agg_k<<<(NN + 3) / 4, 256, 0, stream>>>(
        (const __half2*)feat0h, (const __half2*)feat1h, el0, er0, el1, er1,
        rowptr, csr, gb + (size_t)(l * 2 + 0) * 128,
        gb + (size_t)(l * 2 + 1) * 128, elm, h1h);
  }

  // ---- decision MLP: y = h1h@dw1 (fp16 store, +stats); out = relu(bn(y))@dw2
  mfma_gemm_k<128, 128, _Float16, false, false, true, true, false>
      <<<GB, 256, 0, stream>>>(h1h, dw1t, nullptr, nullptr, nullptr, stats_d,
                               nullptr, ybuf_h, nullptr, NN);
  mfma_gemm_k<128, 32, _Float16, true, false, false, false, true>
      <<<GB, 256, 0, stream>>>(ybuf_h, dw2t, stats_d, dg, db, nullptr,
                               nullptr, nullptr, out, NN);
}

// Round 13
// 841.466 us; speedup vs baseline: 1.7275x; 1.0272x over previous
//
#include <hip/hip_runtime.h>
#include <hip/hip_fp16.h>
#include <math.h>

#define NN 50000
#define EE 800000
#define NHEAD 8
#define BN_EPS 1e-5f
#define NBIN 196            // ceil(NN/256) coarse buckets (dst>>8)
#define NBLK 64             // edge blocks per relation
#define EPB (EE / NBLK)     // 12500 edges per block (exact)
#define SCT (2 * NBIN * NBLK)  // 25088 scan elements

typedef _Float16 half8_t __attribute__((ext_vector_type(8)));
typedef float float4_t __attribute__((ext_vector_type(4)));

// monotone float<->uint encoding for atomicMax on signed floats
__device__ __forceinline__ unsigned fenc(float f) {
  unsigned u = __float_as_uint(f);
  return (u & 0x80000000u) ? ~u : (u | 0x80000000u);
}
__device__ __forceinline__ float fdec(unsigned k) {
  return (k & 0x80000000u) ? __uint_as_float(k & 0x7fffffffu)
                           : __uint_as_float(~k);
}

// bn scale/shift from raw sums (stats[c]=sum, stats[128+c]=sumsq)
__device__ __forceinline__ void bn_coef(const float* __restrict__ stats,
                                        const float* __restrict__ gamma,
                                        const float* __restrict__ beta,
                                        int c, float& sc, float& sh) {
  float mean = stats[c] * (1.f / NN);
  float var = fmaxf(stats[128 + c] * (1.f / NN) - mean * mean, 0.f);
  sc = gamma[c] * rsqrtf(var + BN_EPS);
  sh = beta[c] - mean * sc;
}

// ---------------------------------------------------------------------------
// MFMA GEMM for embed/decision MLPs (unchanged from R12).
// ---------------------------------------------------------------------------
template <int KDIM, int NC, typename AT, bool ABN, bool RESIDBN, bool STATS,
          bool F16OUT, bool F32OUT>
__global__ __launch_bounds__(256)
void mfma_gemm_k(const AT* __restrict__ A, const _Float16* __restrict__ Bt,
                 const float* __restrict__ bn, const float* __restrict__ gamma,
                 const float* __restrict__ beta, float* __restrict__ statsOut,
                 const _Float16* __restrict__ residh, _Float16* __restrict__ Ch,
                 float* __restrict__ Cf, int M) {
  constexpr int NT = NC / 16;
  const int lane = threadIdx.x & 63, wave = threadIdx.x >> 6;
  const int q = lane >> 4, l16 = lane & 15;
  const int row0 = blockIdx.x * 128 + wave * 32;
  float4_t acc[2][NT];
#pragma unroll
  for (int i = 0; i < 2; ++i)
#pragma unroll
    for (int j = 0; j < NT; ++j) acc[i][j] = (float4_t){0.f, 0.f, 0.f, 0.f};

#pragma unroll
  for (int kk = 0; kk < KDIM / 32; ++kk) {
    float scv[8], shv[8];
    if constexpr (ABN) {
      int kb = kk * 32 + q * 8;
#pragma unroll
      for (int x = 0; x < 8; ++x) bn_coef(bn, gamma, beta, kb + x, scv[x], shv[x]);
    }
    half8_t a[2];
#pragma unroll
    for (int i = 0; i < 2; ++i) {
      int r = row0 + i * 16 + l16;
      r = (r < M) ? r : (M - 1);
      if constexpr (__is_same(AT, _Float16)) {
        half8_t hv = *(const half8_t*)(A + (size_t)r * KDIM + kk * 32 + q * 8);
        if constexpr (ABN) {
#pragma unroll
          for (int x = 0; x < 8; ++x)
            hv[x] = (_Float16)fmaxf((float)hv[x] * scv[x] + shv[x], 0.f);
        }
        a[i] = hv;
      } else {
        const float* ap = (const float*)A + (size_t)r * KDIM + kk * 32 + q * 8;
        float4 v0 = *(const float4*)ap, v1 = *(const float4*)(ap + 4);
        float t[8] = {v0.x, v0.y, v0.z, v0.w, v1.x, v1.y, v1.z, v1.w};
        if constexpr (ABN) {
#pragma unroll
          for (int x = 0; x < 8; ++x) t[x] = fmaxf(t[x] * scv[x] + shv[x], 0.f);
        }
        half8_t hv;
#pragma unroll
        for (int x = 0; x < 8; ++x) hv[x] = (_Float16)t[x];
        a[i] = hv;
      }
    }
#pragma unroll
    for (int j = 0; j < NT; ++j) {
      half8_t b = *(const half8_t*)(Bt + (size_t)(j * 16 + l16) * KDIM + kk * 32 + q * 8);
      acc[0][j] = __builtin_amdgcn_mfma_f32_16x16x32_f16(a[0], b, acc[0][j], 0, 0, 0);
      acc[1][j] = __builtin_amdgcn_mfma_f32_16x16x32_f16(a[1], b, acc[1][j], 0, 0, 0);
    }
  }

  float rsc[NT], rsh[NT];
  if constexpr (RESIDBN) {
#pragma unroll
    for (int j = 0; j < NT; ++j) bn_coef(bn, gamma, beta, j * 16 + l16, rsc[j], rsh[j]);
  }
#pragma unroll
  for (int i = 0; i < 2; ++i)
#pragma unroll
    for (int j = 0; j < NT; ++j)
#pragma unroll
      for (int r = 0; r < 4; ++r) {
        int row = row0 + i * 16 + q * 4 + r;   // C/D: col=lane&15, row=q*4+reg
        if (row >= M) continue;
        int col = j * 16 + l16;
        float v = acc[i][j][r];
        if constexpr (RESIDBN) {
          float rv = (float)residh[(size_t)row * NC + col];
          v += fmaxf(rv * rsc[j] + rsh[j], 0.f);
        }
        if constexpr (F32OUT) Cf[(size_t)row * NC + col] = v;
        if constexpr (F16OUT) Ch[(size_t)row * NC + col] = (_Float16)v;
      }

  if constexpr (STATS) {
    float sc_[NT], sq_[NT];
#pragma unroll
    for (int j = 0; j < NT; ++j) {
      float s = 0.f, qq = 0.f;
#pragma unroll
      for (int i = 0; i < 2; ++i)
#pragma unroll
        for (int r = 0; r < 4; ++r) {
          int row = row0 + i * 16 + q * 4 + r;
          float x = (row < M) ? acc[i][j][r] : 0.f;
          s += x; qq += x * x;
        }
      sc_[j] = s; sq_[j] = qq;
    }
#pragma unroll
    for (int j = 0; j < NT; ++j) {
      sc_[j] += __shfl_xor(sc_[j], 16, 64);
      sq_[j] += __shfl_xor(sq_[j], 16, 64);
      sc_[j] += __shfl_xor(sc_[j], 32, 64);
      sq_[j] += __shfl_xor(sq_[j], 32, 64);
    }
    if (lane < 16) {
#pragma unroll
      for (int j = 0; j < NT; ++j) {
        atomicAdd(&statsOut[j * 16 + l16], sc_[j]);
        atomicAdd(&statsOut[128 + j * 16 + l16], sq_[j]);
      }
    }
  }
}

// ---------------------------------------------------------------------------
// Merged per-layer GAT GEMM, NC=288 (unchanged from R12).
// ---------------------------------------------------------------------------
__global__ __launch_bounds__(256)
void feat_gemm_k(const _Float16* __restrict__ A, const _Float16* __restrict__ Bt,
                 _Float16* __restrict__ feat0, _Float16* __restrict__ feat1,
                 float* __restrict__ el0, float* __restrict__ er0,
                 float* __restrict__ el1, float* __restrict__ er1,
                 unsigned* __restrict__ elmax, int M) {
  constexpr int NT = 18;
  const int lane = threadIdx.x & 63, wave = threadIdx.x >> 6;
  const int q = lane >> 4, l16 = lane & 15;
  const int row0 = blockIdx.x * 128 + wave * 32;
  float4_t acc[2][NT];
#pragma unroll
  for (int i = 0; i < 2; ++i)
#pragma unroll
    for (int j = 0; j < NT; ++j) acc[i][j] = (float4_t){0.f, 0.f, 0.f, 0.f};

#pragma unroll
  for (int kk = 0; kk < 4; ++kk) {
    half8_t a[2];
#pragma unroll
    for (int i = 0; i < 2; ++i) {
      int r = row0 + i * 16 + l16;
      r = (r < M) ? r : (M - 1);
      a[i] = *(const half8_t*)(A + (size_t)r * 128 + kk * 32 + q * 8);
    }
#pragma unroll
    for (int j = 0; j < NT; ++j) {
      half8_t b = *(const half8_t*)(Bt + (size_t)(j * 16 + l16) * 128 + kk * 32 + q * 8);
      acc[0][j] = __builtin_amdgcn_mfma_f32_16x16x32_f16(a[0], b, acc[0][j], 0, 0, 0);
      acc[1][j] = __builtin_amdgcn_mfma_f32_16x16x32_f16(a[1], b, acc[1][j], 0, 0, 0);
    }
  }

#pragma unroll
  for (int i = 0; i < 2; ++i)
#pragma unroll
    for (int r = 0; r < 4; ++r) {
      int row = row0 + i * 16 + q * 4 + r;
      if (row >= M) continue;
#pragma unroll
      for (int j = 0; j < 16; ++j) {
        float v = acc[i][j][r];
        if (j < 8)
          feat0[(size_t)row * 128 + j * 16 + l16] = (_Float16)v;
        else
          feat1[(size_t)row * 128 + (j - 8) * 16 + l16] = (_Float16)v;
      }
      {
        float v = acc[i][16][r];
        if (l16 < 8) el0[(size_t)row * 8 + l16] = v;
        else         er0[(size_t)row * 8 + (l16 - 8)] = v;
        v = acc[i][17][r];
        if (l16 < 8) el1[(size_t)row * 8 + l16] = v;
        else         er1[(size_t)row * 8 + (l16 - 8)] = v;
      }
    }

  float m0 = -1e30f, m1 = -1e30f;
#pragma unroll
  for (int i = 0; i < 2; ++i)
#pragma unroll
    for (int r = 0; r < 4; ++r) {
      m0 = fmaxf(m0, acc[i][16][r]);
      m1 = fmaxf(m1, acc[i][17][r]);
    }
  m0 = fmaxf(m0, __shfl_xor(m0, 16, 64)); m0 = fmaxf(m0, __shfl_xor(m0, 32, 64));
  m1 = fmaxf(m1, __shfl_xor(m1, 16, 64)); m1 = fmaxf(m1, __shfl_xor(m1, 32, 64));
  if (q == 0 && l16 < 8) {
    atomicMax(&elmax[l16], fenc(m0));
    atomicMax(&elmax[8 + l16], fenc(m1));
  }
}

// ---------------------------------------------------------------------------
// Build: weight transposes + merged Bt + zero elmax/stats. 9 blocks.
// ---------------------------------------------------------------------------
__global__ __launch_bounds__(256)
void build_k(const float* __restrict__ ew1, const float* __restrict__ ew2,
             const float* __restrict__ dw1, const float* __restrict__ dw2,
             const float* __restrict__ gfc, const float* __restrict__ gal,
             const float* __restrict__ gar, _Float16* __restrict__ ew1t,
             _Float16* __restrict__ ew2t, _Float16* __restrict__ dw1t,
             _Float16* __restrict__ dw2t, _Float16* __restrict__ bt,
             float* __restrict__ statsz, unsigned* __restrict__ elmax) {
  int b = blockIdx.x;
  if (b < 4) {  // layer b merged Bt [288][128]
    _Float16* dst = bt + (size_t)b * 288 * 128;
    for (int idx = threadIdx.x; idx < 288 * 128; idx += 256) {
      int c = idx >> 7, k = idx & 127;
      float v;
      if (c < 128) {
        v = gfc[(size_t)(2 * b) * 16384 + k * 128 + c];
      } else if (c < 256) {
        v = gfc[(size_t)(2 * b + 1) * 16384 + k * 128 + (c - 128)];
      } else {
        int sub = c - 256, blk = sub >> 3, h = sub & 7;
        int r = blk >> 1;
        const float* attn = (blk & 1) ? gar : gal;
        const float* W = gfc + (size_t)(2 * b + r) * 16384;
        const float* av = attn + (size_t)(2 * b + r) * 128 + h * 16;
        float s = 0.f;
#pragma unroll
        for (int d = 0; d < 16; ++d) s += W[k * 128 + h * 16 + d] * av[d];
        v = s;
      }
      dst[idx] = (_Float16)v;  // idx == c*128 + k
    }
  } else if (b < 8) {
    int j = b - 4;
    const float* srcs[4] = {ew1, ew2, dw1, dw2};
    _Float16* dsts[4] = {ew1t, ew2t, dw1t, dw2t};
    const int ks[4] = {64, 128, 128, 128}, ns[4] = {128, 128, 128, 32};
    int k = ks[j], nn = ns[j], total = k * nn;
    for (int i = threadIdx.x; i < total; i += 256) {
      int kk = i / nn, cc = i % nn;
      dsts[j][(size_t)cc * k + kk] = (_Float16)srcs[j][i];
    }
  } else {
    if (threadIdx.x < 64) elmax[threadIdx.x] = 0u;
    for (int i = threadIdx.x; i < 1024; i += 256) statsz[i] = 0.f;
  }
}

// ---------------------------------------------------------------------------
// CSR via counting sort (no global atomics, no scatter amplification):
// K1 bhist: per-(rel,block) LDS histogram of dst>>8 into bcnt[rel][bin][blk].
// K2 bscan: single-block exclusive scan of all 25088 counts (global order).
// K3 bscat: scatter packed (src | dst<<16) into bucket-contiguous segments.
// K4 bfin:  per-bucket (256 nodes) LDS hist+scan -> coalesced rowptr + csr.
// ---------------------------------------------------------------------------
__global__ __launch_bounds__(256)
void bhist_k(const int* __restrict__ dst, int* __restrict__ bcnt) {
  int r = blockIdx.y, blk = blockIdx.x;
  __shared__ int bins[NBIN];
  for (int i = threadIdx.x; i < NBIN; i += 256) bins[i] = 0;
  __syncthreads();
  const int* d = dst + (size_t)r * EE;
  int e0 = blk * EPB;
  for (int e = e0 + threadIdx.x; e < e0 + EPB; e += 256)
    atomicAdd(&bins[d[e] >> 8], 1);
  __syncthreads();
  for (int i = threadIdx.x; i < NBIN; i += 256)
    bcnt[(size_t)(r * NBIN + i) * NBLK + blk] = bins[i];
}

__global__ __launch_bounds__(256)
void bscan_k(int* __restrict__ bcnt) {  // in-place exclusive scan of SCT elems
  __shared__ int sh[256];
  const int chunk = SCT / 256;  // 98 (exact)
  int t = threadIdx.x;
  int lo = t * chunk;
  int s = 0;
  for (int i = lo; i < lo + chunk; ++i) s += bcnt[i];
  sh[t] = s;
  __syncthreads();
#pragma unroll
  for (int off = 1; off < 256; off <<= 1) {
    int tv = (t >= off) ? sh[t - off] : 0;
    __syncthreads();
    sh[t] += tv;
    __syncthreads();
  }
  int run = sh[t] - s;  // exclusive base for this chunk
  for (int i = lo; i < lo + chunk; ++i) {
    int v = bcnt[i];
    bcnt[i] = run;
    run += v;
  }
}

__global__ __launch_bounds__(256)
void bscat_k(const int* __restrict__ src, const int* __restrict__ dst,
             const int* __restrict__ bcnt, unsigned* __restrict__ packed) {
  int r = blockIdx.y, blk = blockIdx.x;
  __shared__ int base[NBIN];
  for (int i = threadIdx.x; i < NBIN; i += 256)
    base[i] = bcnt[(size_t)(r * NBIN + i) * NBLK + blk];
  __syncthreads();
  const int* d = dst + (size_t)r * EE;
  const int* s = src + (size_t)r * EE;
  int e0 = blk * EPB;
  for (int e = e0 + threadIdx.x; e < e0 + EPB; e += 256) {
    int dd = d[e];
    int pos = atomicAdd(&base[dd >> 8], 1);
    packed[pos] = (unsigned)s[e] | ((unsigned)dd << 16);
  }
}

__global__ __launch_bounds__(256)
void bfin_k(const unsigned* __restrict__ packed, const int* __restrict__ bcnt,
            int* __restrict__ rowptr, unsigned short* __restrict__ csr) {
  int f = blockIdx.x;  // 0 .. 2*NBIN-1
  int r = f / NBIN, b = f % NBIN;
  __shared__ int deg[256], pref[256], pos[256];
  int start = bcnt[(size_t)f * NBLK];
  int end = (f + 1 < 2 * NBIN) ? bcnt[(size_t)(f + 1) * NBLK] : 2 * EE;
  deg[threadIdx.x] = 0;
  __syncthreads();
  for (int e = start + threadIdx.x; e < end; e += 256)
    atomicAdd(&deg[(packed[e] >> 16) & 255], 1);
  __syncthreads();
  int v = deg[threadIdx.x];
  pref[threadIdx.x] = v;
  __syncthreads();
#pragma unroll
  for (int off = 1; off < 256; off <<= 1) {
    int tv = (threadIdx.x >= off) ? pref[threadIdx.x - off] : 0;
    __syncthreads();
    pref[threadIdx.x] += tv;
    __syncthreads();
  }
  int excl = pref[threadIdx.x] - v;
  int node = b * 256 + threadIdx.x;
  if (node < NN) rowptr[r * (NN + 1) + node] = start - r * EE + excl;
  if (node == NN) rowptr[r * (NN + 1) + NN] = EE;
  pos[threadIdx.x] = start + excl;
  __syncthreads();
  for (int e = start + threadIdx.x; e < end; e += 256) {
    unsigned pk = packed[e];
    int local = (pk >> 16) & 255;
    int p = atomicAdd(&pos[local], 1);
    csr[p] = (unsigned short)(pk & 0xffffu);
  }
}

// ---------------------------------------------------------------------------
// GAT aggregate (unchanged from R12): both relations interleaved, 16 gathers
// in flight, lane-specialized bound-shift softmax, fp16 residual stream.
// ---------------------------------------------------------------------------
__global__ __launch_bounds__(256)
void gat_agg_k(const __half2* __restrict__ f0, const __half2* __restrict__ f1,
               const float* __restrict__ el0, const float* __restrict__ er0,
               const float* __restrict__ el1, const float* __restrict__ er1,
               const int* __restrict__ rowptr, const unsigned short* __restrict__ csr,
               const float* __restrict__ b0, const float* __restrict__ b1,
               const unsigned* __restrict__ elmax,
               _Float16* __restrict__ h1h) {
  int n = blockIdx.x * 4 + (threadIdx.x >> 6);
  if (n >= NN) return;
  int lane = threadIdx.x & 63;
  int head = lane >> 3, eslot = lane & 7;
  float er0h = er0[(size_t)n * 8 + head];
  float er1h = er1[(size_t)n * 8 + head];
  float bnd0 = fdec(elmax[head]) + er0h;       bnd0 = fmaxf(bnd0, 0.2f * bnd0);
  float bnd1 = fdec(elmax[8 + head]) + er1h;   bnd1 = fmaxf(bnd1, 0.2f * bnd1);
  int beg0 = rowptr[n], end0 = rowptr[n + 1];
  const int* rp1 = rowptr + (NN + 1);
  int beg1 = rp1[n], end1 = rp1[n + 1];
  const unsigned short* csr1 = csr + EE;
  int len = max(end0 - beg0, end1 - beg1);

  float ls0 = 0.f, a00 = 0.f, a01 = 0.f;
  float ls1 = 0.f, a10 = 0.f, a11 = 0.f;
  for (int t = 0; t < len; t += 8) {
    int t0 = beg0 + t, t1 = beg1 + t;
    int s0[8], s1[8];
#pragma unroll
    for (int j = 0; j < 8; ++j) {
      s0[j] = (int)csr[max(min(t0 + j, end0 - 1), 0)];
      s1[j] = (int)csr1[max(min(t1 + j, end1 - 1), 0)];
    }
    int so0 = (int)csr[max(min(t0 + eslot, end0 - 1), 0)];
    int so1 = (int)csr1[max(min(t1 + eslot, end1 - 1), 0)];
    float ev0 = el0[(size_t)so0 * 8 + head];
    float ev1 = el1[(size_t)so1 * 8 + head];
    __half2 g0[8], g1[8];
#pragma unroll
    for (int j = 0; j < 8; ++j) {
      g0[j] = f0[(size_t)s0[j] * 64 + lane];
      g1[j] = f1[(size_t)s1[j] * 64 + lane];
    }
    float e0 = ev0 + er0h; e0 = fmaxf(e0, 0.2f * e0);
    float p0 = __expf(e0 - bnd0);
    p0 = (t0 + eslot < end0) ? p0 : 0.f;
    float e1 = ev1 + er1h; e1 = fmaxf(e1, 0.2f * e1);
    float p1 = __expf(e1 - bnd1);
    p1 = (t1 + eslot < end1) ? p1 : 0.f;
#pragma unroll
    for (int j = 0; j < 8; ++j) {
      float pj0 = __shfl(p0, (lane & 56) | j);
      float pj1 = __shfl(p1, (lane & 56) | j);
      float2 v0 = __half22float2(g0[j]);
      float2 v1 = __half22float2(g1[j]);
      ls0 += pj0; a00 += pj0 * v0.x; a01 += pj0 * v0.y;
      ls1 += pj1; a10 += pj1 * v1.x; a11 += pj1 * v1.y;
    }
  }
  float inv0 = (ls0 > 0.f) ? 1.f / ls0 : 0.f;  // isolated node -> rst = 0
  float inv1 = (ls1 > 0.f) ? 1.f / ls1 : 0.f;
  float t0 = a00 * inv0 + a10 * inv1 + b0[lane * 2] + b1[lane * 2];
  float t1 = a01 * inv0 + a11 * inv1 + b0[lane * 2 + 1] + b1[lane * 2 + 1];
  t0 = (t0 > 0.f) ? t0 : 0.01f * t0;           // leaky_relu 0.01
  t1 = (t1 > 0.f) ? t1 : 0.01f * t1;
  __half2* hh = (__half2*)h1h + (size_t)n * 64 + lane;
  float2 h = __half22float2(*hh);
  h.x += t0; h.y += t1;
  *hh = __floats2half2_rn(h.x, h.y);
}

// ---------------------------------------------------------------------------
extern "C" void kernel_launch(void* const* d_in, const int* in_sizes, int n_in,
                              void* d_out, int out_size, void* d_ws,
                              size_t ws_size, hipStream_t stream) {
  const float* inputs = (const float*)d_in[0];
  const int* src = (const int*)d_in[1];
  const int* dst = (const int*)d_in[2];
  const float* ew1 = (const float*)d_in[3];
  const float* eg = (const float*)d_in[4];
  const float* eb = (const float*)d_in[5];
  const float* ew2 = (const float*)d_in[6];
  const float* gfc = (const float*)d_in[7];
  const float* gal = (const float*)d_in[8];
  const float* gar = (const float*)d_in[9];
  const float* gb = (const float*)d_in[10];
  const float* dw1 = (const float*)d_in[11];
  const float* dg = (const float*)d_in[12];
  const float* db = (const float*)d_in[13];
  const float* dw2 = (const float*)d_in[14];
  float* out = (float*)d_out;

  // ---- workspace layout (~56 MB) ----
  char* p = (char*)d_ws;
  // region A (25.6MB): ybuf_h (MLP phases) | feat0h+feat1h (GAT phase)
  _Float16* feat0h = (_Float16*)p;
  _Float16* feat1h = feat0h + (size_t)NN * 128;
  _Float16* ybuf_h = feat0h;        // alias: MLP and GAT phases don't overlap
  p += (size_t)NN * 128 * 4;
  _Float16* h1h = (_Float16*)p;     p += (size_t)NN * 128 * 2;   // 12.8MB
  float* el0 = (float*)p;           p += (size_t)NN * NHEAD * 4;
  float* er0 = (float*)p;           p += (size_t)NN * NHEAD * 4;
  float* el1 = (float*)p;           p += (size_t)NN * NHEAD * 4;
  float* er1 = (float*)p;           p += (size_t)NN * NHEAD * 4;
  float* stats = (float*)p;         p += 1024 * 4;  // stats_e | stats_d
  float* stats_e = stats;
  float* stats_d = stats + 512;
  _Float16* ew1t = (_Float16*)p;    p += (size_t)64 * 128 * 2;
  _Float16* ew2t = (_Float16*)p;    p += (size_t)128 * 128 * 2;
  _Float16* dw1t = (_Float16*)p;    p += (size_t)128 * 128 * 2;
  _Float16* dw2t = (_Float16*)p;    p += (size_t)32 * 128 * 2;
  _Float16* bt = (_Float16*)p;      p += (size_t)4 * 288 * 128 * 2;
  int* rowptr = (int*)p;            p += (size_t)2 * (NN + 1) * 4;
  unsigned short* csr = (unsigned short*)p;   p += (size_t)2 * EE * 2;
  unsigned* packed = (unsigned*)p;  p += (size_t)2 * EE * 4;    // 6.4MB
  int* bcnt = (int*)p;              p += (size_t)SCT * 4;       // 100KB
  unsigned* elmaxAll = (unsigned*)p;  // 64 uints (4 layers x 16)

  const int GB = (NN + 127) / 128;  // 391

  // ---- build (weights + zero elmax/stats) + counting-sort CSR ----
  build_k<<<9, 256, 0, stream>>>(ew1, ew2, dw1, dw2, gfc, gal, gar,
                                 ew1t, ew2t, dw1t, dw2t, bt, stats, elmaxAll);
  bhist_k<<<dim3(NBLK, 2), 256, 0, stream>>>(dst, bcnt);
  bscan_k<<<1, 256, 0, stream>>>(bcnt);
  bscat_k<<<dim3(NBLK, 2), 256, 0, stream>>>(src, dst, bcnt, packed);
  bfin_k<<<2 * NBIN, 256, 0, stream>>>(packed, bcnt, rowptr, csr);

  // ---- embed MLP: y=x@w1 (fp16 store, +stats); h1h=relu(bn(y))@w2+relu(bn(y))
  mfma_gemm_k<64, 128, float, false, false, true, true, false>
      <<<GB, 256, 0, stream>>>(inputs, ew1t, nullptr, nullptr, nullptr,
                               stats_e, nullptr, ybuf_h, nullptr, NN);
  mfma_gemm_k<128, 128, _Float16, true, true, false, true, false>
      <<<GB, 256, 0, stream>>>(ybuf_h, ew2t, stats_e, eg, eb, nullptr,
                               ybuf_h, h1h, nullptr, NN);

  // ---- 4 GAT layers: merged GEMM(+el/er/elmax) then aggregate ----
  for (int l = 0; l < 4; ++l) {
    unsigned* elm = elmaxAll + l * 16;
    feat_gemm_k<<<GB, 256, 0, stream>>>(
        h1h, bt + (size_t)l * 288 * 128, feat0h, feat1h,
        el0, er0, el1, er1, elm, NN);
    gat_agg_k<<<(NN + 3) / 4, 256, 0, stream>>>(
        (const __half2*)feat0h, (const __half2*)feat1h, el0, er0, el1, er1,
        rowptr, csr, gb + (size_t)(l * 2 + 0) * 128,
        gb + (size_t)(l * 2 + 1) * 128, elm, h1h);
  }

  // ---- decision MLP: y = h1h@dw1 (fp16 store, +stats); out = relu(bn(y))@dw2
  mfma_gemm_k<128, 128, _Float16, false, false, true, true, false>
      <<<GB, 256, 0, stream>>>(h1h, dw1t, nullptr, nullptr, nullptr, stats_d,
                               nullptr, ybuf_h, nullptr, NN);
  mfma_gemm_k<128, 32, _Float16, true, false, false, false, true>
      <<<GB, 256, 0, stream>>>(ybuf_h, dw2t, stats_d, dg, db, nullptr,
                               nullptr, nullptr, out, NN);
}